// Round 2
// baseline (1587.610 us; speedup 1.0000x reference)
//
#include <hip/hip_runtime.h>
#include <hip/hip_bf16.h>

// Problem constants (Mp_encoder): N nodes, D dims, P metapaths.
constexpr int N = 4096;
constexpr int D = 256;
constexpr int P = 3;
constexpr int MAXDEG = 17;       // K+1
constexpr float TAU = 0.8f;
constexpr float MARGIN = 0.1f;
constexpr float EPS_PD = 1e-6f;

// Uniform-branch input load: dataset stores inputs either bf16 or fp32; a
// device flag (detected from mps sparsity bit-patterns) selects the stride.
__device__ inline float load_in(const void* p, size_t i, int bf) {
    return bf ? __bfloat162float(((const __hip_bfloat16*)p)[i])
              : ((const float*)p)[i];
}

// ---------------------------------------------------------------------------
// 0. dtype detection: count 32-bit words of mps with zero high half but
//    nonzero low half. bf16 storage: ~0.2% of words (sparse values landing in
//    even element slots). fp32 storage: 0 (all values are 0 or >= 2^-5).
// ---------------------------------------------------------------------------
__global__ void detect_dtype(const unsigned int* __restrict__ w, int nwords,
                             int* __restrict__ counter) {
    int stride = gridDim.x * blockDim.x;
    int c = 0;
    for (int i = blockIdx.x * blockDim.x + threadIdx.x; i < nwords; i += stride) {
        unsigned int x = w[i];
        if ((x & 0xFFFF0000u) == 0u && x != 0u) c++;
    }
    for (int s = 32; s > 0; s >>= 1) c += __shfl_down(c, s);
    if ((threadIdx.x & 63) == 0 && c > 0) atomicAdd(counter, c);
}
__global__ void finalize_flag(const int* __restrict__ counter, int* __restrict__ flag) {
    flag[0] = (counter[0] > 100) ? 1 : 0;
}

// ---------------------------------------------------------------------------
// 1. Sparse extraction: per (p,n) row of mps, nnz (<=17) sorted ascending,
//    deg, and the 17 smallest non-neighbor indices (stable-argsort semantics).
// ---------------------------------------------------------------------------
__global__ void extract_sparse(const void* __restrict__ mps, const int* __restrict__ dflag,
                               int* __restrict__ nbr_idx, float* __restrict__ nbr_val,
                               int* __restrict__ neg_idx, int* __restrict__ deg) {
    int bf = dflag[0];
    int row = blockIdx.x;              // 0 .. P*N-1
    __shared__ int cnt;
    __shared__ int sidx[32];
    __shared__ float sval[32];
    if (threadIdx.x == 0) cnt = 0;
    __syncthreads();
    for (int c = threadIdx.x; c < N; c += blockDim.x) {
        float v = load_in(mps, (size_t)row * N + c, bf);
        if (v > 0.f) {
            int k = atomicAdd(&cnt, 1);
            if (k < 32) { sidx[k] = c; sval[k] = v; }
        }
    }
    __syncthreads();
    if (threadIdx.x == 0) {
        int dg = cnt; if (dg > MAXDEG) dg = MAXDEG;
        for (int i = 1; i < dg; i++) {           // insertion sort by index
            int ki = sidx[i]; float kv = sval[i]; int j = i - 1;
            while (j >= 0 && sidx[j] > ki) { sidx[j+1] = sidx[j]; sval[j+1] = sval[j]; j--; }
            sidx[j+1] = ki; sval[j+1] = kv;
        }
        deg[row] = dg;
        int* oi = nbr_idx + (size_t)row * MAXDEG;
        float* ov = nbr_val + (size_t)row * MAXDEG;
        int* ng = neg_idx + (size_t)row * MAXDEG;
        for (int i = 0; i < MAXDEG; i++) { oi[i] = (i < dg) ? sidx[i] : 0; ov[i] = (i < dg) ? sval[i] : 0.f; }
        int c = 0, j = 0, found = 0;
        while (found < MAXDEG) {
            if (j < dg && sidx[j] == c) { j++; c++; continue; }
            ng[found++] = c++;
        }
    }
}

// ---------------------------------------------------------------------------
// 2. C[N x D] = act(A[N x D] @ W[D x D]^T + bias). ACT: 0 none, 1 elu, 2 tanh
//    A_IN: A is an external input (flag-typed); else fp32 workspace.
// ---------------------------------------------------------------------------
template <bool A_IN, int ACT>
__global__ void gemm_ndd(const void* __restrict__ A, const void* __restrict__ W,
                         size_t wOff, const void* __restrict__ bias, size_t bOff,
                         const int* __restrict__ dflag, float* __restrict__ C) {
    int bf = dflag[0];
    __shared__ float As[16][65];
    __shared__ float Ws[16][65];
    int bm = blockIdx.x * 64;
    int bn = blockIdx.y * 64;
    int tid = threadIdx.x;
    int tx = tid & 15, ty = tid >> 4;
    float acc[4][4] = {};
    for (int k0 = 0; k0 < D; k0 += 16) {
        for (int e = tid; e < 64 * 16; e += 256) {
            int r = e >> 4, k = e & 15;
            As[k][r] = A_IN ? load_in(A, (size_t)(bm + r) * D + k0 + k, bf)
                            : ((const float*)A)[(size_t)(bm + r) * D + k0 + k];
            Ws[k][r] = load_in(W, wOff + (size_t)(bn + r) * D + k0 + k, bf);
        }
        __syncthreads();
        #pragma unroll
        for (int k = 0; k < 16; k++) {
            float a[4], w[4];
            #pragma unroll
            for (int i = 0; i < 4; i++) a[i] = As[k][ty * 4 + i];
            #pragma unroll
            for (int j = 0; j < 4; j++) w[j] = Ws[k][tx * 4 + j];
            #pragma unroll
            for (int i = 0; i < 4; i++)
                #pragma unroll
                for (int j = 0; j < 4; j++) acc[i][j] += a[i] * w[j];
        }
        __syncthreads();
    }
    #pragma unroll
    for (int i = 0; i < 4; i++) {
        int r = bm + ty * 4 + i;
        #pragma unroll
        for (int j = 0; j < 4; j++) {
            int c = bn + tx * 4 + j;
            float v = acc[i][j];
            if (bias) v += load_in(bias, bOff + c, bf);
            if (ACT == 1) v = v > 0.f ? v : expm1f(v);
            if (ACT == 2) v = tanhf(v);
            C[(size_t)r * D + c] = v;
        }
    }
}

// ---------------------------------------------------------------------------
// 3. emb[n][d] = prelu( sum_k val_k * X[idx_k][d] + bias[d] )
// ---------------------------------------------------------------------------
__global__ void spmm_prelu(const float* __restrict__ X, const int* __restrict__ nbr_idx,
                           const float* __restrict__ nbr_val, const int* __restrict__ deg,
                           const void* __restrict__ bias, size_t bOff,
                           const void* __restrict__ prelu_a, int p,
                           const int* __restrict__ dflag, float* __restrict__ emb) {
    int bf = dflag[0];
    int n = blockIdx.x;
    int d = threadIdx.x;
    const int* idx = nbr_idx + (size_t)n * MAXDEG;
    const float* val = nbr_val + (size_t)n * MAXDEG;
    int dg = deg[n];
    float acc = 0.f;
    for (int k = 0; k < dg; k++) acc += val[k] * X[(size_t)idx[k] * D + d];
    acc += load_in(bias, bOff + d, bf);
    float a = load_in(prelu_a, p, bf);
    emb[(size_t)n * D + d] = acc > 0.f ? acc : a * acc;
}

// ---------------------------------------------------------------------------
// 4. Column sums (for attention mean)
// ---------------------------------------------------------------------------
__global__ void colsum_acc(const float* __restrict__ T, float* __restrict__ spacc) {
    int d = threadIdx.x;
    int r0 = blockIdx.x * (N / 16);
    float s = 0.f;
    for (int r = r0; r < r0 + N / 16; r++) s += T[(size_t)r * D + d];
    atomicAdd(&spacc[d], s);
}

// ---------------------------------------------------------------------------
// 5. Row-normalize (in place)
// ---------------------------------------------------------------------------
__global__ void rownorm(float* __restrict__ Pm) {
    int n = blockIdx.x;
    float* row = Pm + (size_t)n * D;
    int t = threadIdx.x;
    float v = row[t];
    __shared__ float red[256];
    red[t] = v * v;
    __syncthreads();
    for (int s = 128; s > 0; s >>= 1) { if (t < s) red[t] += red[t + s]; __syncthreads(); }
    float inv = rsqrtf(red[0]);
    row[t] = v * inv;
}

// ---------------------------------------------------------------------------
// 6. sim tile: S = exp(Qa @ Qb^T / TAU); accumulate rowsum & colsum.
// ---------------------------------------------------------------------------
__global__ void sim_pair(const float* __restrict__ Qa, const float* __restrict__ Qb,
                         float* __restrict__ rowsum, float* __restrict__ colsum) {
    __shared__ float As[16][65];
    __shared__ float Bs[16][65];
    __shared__ float rred[64], cred[64];
    int bm = blockIdx.x * 64, bn = blockIdx.y * 64;
    int tid = threadIdx.x, tx = tid & 15, ty = tid >> 4;
    if (tid < 64) { rred[tid] = 0.f; cred[tid] = 0.f; }
    float acc[4][4] = {};
    for (int k0 = 0; k0 < D; k0 += 16) {
        for (int e = tid; e < 1024; e += 256) {
            int r = e >> 4, k = e & 15;
            As[k][r] = Qa[(size_t)(bm + r) * D + k0 + k];
            Bs[k][r] = Qb[(size_t)(bn + r) * D + k0 + k];
        }
        __syncthreads();
        #pragma unroll
        for (int k = 0; k < 16; k++) {
            float a[4], b[4];
            #pragma unroll
            for (int i = 0; i < 4; i++) a[i] = As[k][ty * 4 + i];
            #pragma unroll
            for (int j = 0; j < 4; j++) b[j] = Bs[k][tx * 4 + j];
            #pragma unroll
            for (int i = 0; i < 4; i++)
                #pragma unroll
                for (int j = 0; j < 4; j++) acc[i][j] += a[i] * b[j];
        }
        __syncthreads();
    }
    const float invtau = 1.0f / TAU;
    float rpart[4] = {0.f, 0.f, 0.f, 0.f};
    float cpart[4] = {0.f, 0.f, 0.f, 0.f};
    #pragma unroll
    for (int i = 0; i < 4; i++)
        #pragma unroll
        for (int j = 0; j < 4; j++) {
            float e = __expf(acc[i][j] * invtau);
            rpart[i] += e;
            cpart[j] += e;
        }
    #pragma unroll
    for (int i = 0; i < 4; i++) atomicAdd(&rred[ty * 4 + i], rpart[i]);
    #pragma unroll
    for (int j = 0; j < 4; j++) atomicAdd(&cred[tx * 4 + j], cpart[j]);
    __syncthreads();
    if (tid < 64) atomicAdd(&rowsum[bm + tid], rred[tid]);
    else if (tid < 128) atomicAdd(&colsum[bn + tid - 64], cred[tid - 64]);
}

// ---------------------------------------------------------------------------
// 7. pos-weighted sums
// ---------------------------------------------------------------------------
__global__ void posdot(const float* __restrict__ Qa, const float* __restrict__ Qb,
                       const int* __restrict__ nbr_idx, const float* __restrict__ nbr_val,
                       const int* __restrict__ deg,
                       float* __restrict__ pdrow, float* __restrict__ pdcol) {
    int n = blockIdx.x;
    int wv = threadIdx.x >> 6, lane = threadIdx.x & 63;
    int dg = deg[n];
    const int* idx = nbr_idx + (size_t)n * MAXDEG;
    const float* val = nbr_val + (size_t)n * MAXDEG;
    __shared__ float srow[MAXDEG], scol[MAXDEG];
    const float invtau = 1.0f / TAU;
    for (int k = wv; k < dg; k += 4) {
        int j = idx[k];
        float dr = 0.f, dc = 0.f;
        for (int t = lane; t < D; t += 64) {
            dr += Qa[(size_t)n * D + t] * Qb[(size_t)j * D + t];
            dc += Qa[(size_t)j * D + t] * Qb[(size_t)n * D + t];
        }
        for (int s = 32; s > 0; s >>= 1) { dr += __shfl_down(dr, s); dc += __shfl_down(dc, s); }
        if (lane == 0) { srow[k] = __expf(dr * invtau) * val[k]; scol[k] = __expf(dc * invtau) * val[k]; }
    }
    __syncthreads();
    if (threadIdx.x == 0) {
        float sr = 0.f, sc = 0.f;
        for (int k = 0; k < dg; k++) { sr += srow[k]; sc += scol[k]; }
        pdrow[n] = sr; pdcol[n] = sc;
    }
}

// ---------------------------------------------------------------------------
// 8. pair loss
// ---------------------------------------------------------------------------
__global__ void pair_loss(const float* __restrict__ rowsum, const float* __restrict__ colsum,
                          const float* __restrict__ pdrow, const float* __restrict__ pdcol,
                          float* __restrict__ loss) {
    int n = blockIdx.x * blockDim.x + threadIdx.x;
    float l12 = -logf(pdrow[n] / (rowsum[n] + 1e-8f));
    float l21 = -logf(pdcol[n] / (colsum[n] + 1e-8f));
    float l = (0.5f * l12 + 0.5f * l21) / (float)N;
    __shared__ float red[256];
    red[threadIdx.x] = l;
    __syncthreads();
    for (int s = 128; s > 0; s >>= 1) { if (threadIdx.x < s) red[threadIdx.x] += red[threadIdx.x + s]; __syncthreads(); }
    if (threadIdx.x == 0) atomicAdd(loss, red[0]);
}

// ---------------------------------------------------------------------------
// 9. node loss (per metapath)
// ---------------------------------------------------------------------------
__global__ void node_loss_k(const float* __restrict__ emb, const int* __restrict__ nbr_idx,
                            const int* __restrict__ neg_idx, const int* __restrict__ deg,
                            float* __restrict__ loss) {
    int n = blockIdx.x;
    int wv = threadIdx.x >> 6, lane = threadIdx.x & 63;
    int dg = deg[n];
    __shared__ float per[MAXDEG];
    const float* en = emb + (size_t)n * D;
    for (int k = wv; k < dg; k += 4) {
        int jp = nbr_idx[(size_t)n * MAXDEG + k];
        int jn = neg_idx[(size_t)n * MAXDEG + k];
        const float* ep = emb + (size_t)jp * D;
        const float* eg = emb + (size_t)jn * D;
        float dp = 0.f, dn = 0.f;
        for (int t = lane; t < D; t += 64) {
            float a = en[t];
            float x = a - ep[t] + EPS_PD; dp += x * x;
            float y = a - eg[t] + EPS_PD; dn += y * y;
        }
        for (int s = 32; s > 0; s >>= 1) { dp += __shfl_down(dp, s); dn += __shfl_down(dn, s); }
        if (lane == 0) { float v = dp - dn + MARGIN; per[k] = v > 0.f ? v : 0.f; }
    }
    __syncthreads();
    if (threadIdx.x == 0) {
        float s = 0.f;
        for (int k = 0; k < dg; k++) s += per[k];
        atomicAdd(loss, s / (float)dg);
    }
}

// ---------------------------------------------------------------------------
// 10. beta = softmax over p of (spacc[p]/N . att_vec)
// ---------------------------------------------------------------------------
__global__ void beta_k(const float* __restrict__ spacc, const void* __restrict__ av,
                       const int* __restrict__ dflag, float* __restrict__ beta) {
    int bf = dflag[0];
    __shared__ float red[256];
    __shared__ float w[P];
    int t = threadIdx.x;
    for (int p = 0; p < P; p++) {
        float v = (spacc[p * D + t] / (float)N) * load_in(av, t, bf);
        red[t] = v;
        __syncthreads();
        for (int s = 128; s > 0; s >>= 1) { if (t < s) red[t] += red[t + s]; __syncthreads(); }
        if (t == 0) w[p] = red[0];
        __syncthreads();
    }
    if (t == 0) {
        float m = fmaxf(w[0], fmaxf(w[1], w[2]));
        float e0 = __expf(w[0] - m), e1 = __expf(w[1] - m), e2 = __expf(w[2] - m);
        float s = e0 + e1 + e2;
        beta[0] = e0 / s; beta[1] = e1 / s; beta[2] = e2 / s;
    }
}

// ---------------------------------------------------------------------------
// 11. z_mp output + loss scalar (output dtype follows detected input dtype)
// ---------------------------------------------------------------------------
__global__ void zmp_out(const float* __restrict__ e0, const float* __restrict__ e1,
                        const float* __restrict__ e2, const float* __restrict__ beta,
                        const float* __restrict__ loss, const int* __restrict__ dflag,
                        void* __restrict__ out) {
    int bf = dflag[0];
    int i = blockIdx.x * 256 + threadIdx.x;
    float v = beta[0] * e0[i] + beta[1] * e1[i] + beta[2] * e2[i];
    if (bf) {
        __hip_bfloat16* o = (__hip_bfloat16*)out;
        o[i] = __float2bfloat16(v);
        if (i == 0) o[(size_t)N * D] = __float2bfloat16(*loss);
    } else {
        float* o = (float*)out;
        o[i] = v;
        if (i == 0) o[(size_t)N * D] = *loss;
    }
}

extern "C" void kernel_launch(void* const* d_in, const int* in_sizes, int n_in,
                              void* d_out, int out_size, void* d_ws, size_t ws_size,
                              hipStream_t stream) {
    const void* h        = d_in[0];
    const void* mps      = d_in[1];
    const void* W_gcn    = d_in[2];
    const void* b_gcn    = d_in[3];
    const void* prelu_a  = d_in[4];
    const void* att_fc_W = d_in[5];
    const void* att_fc_b = d_in[6];
    const void* att_vec  = d_in[7];
    const void* proj_W1  = d_in[8];
    const void* proj_b1  = d_in[9];
    const void* proj_W2  = d_in[10];
    const void* proj_b2  = d_in[11];

    char* ws = (char*)d_ws;
    size_t off = 0;
    auto alloc = [&](size_t bytes) -> char* {
        char* p = ws + off;
        off = (off + bytes + 255) & ~(size_t)255;
        return p;
    };
    float* emb[P];  for (int p = 0; p < P; p++) emb[p]  = (float*)alloc((size_t)N * D * 4);
    float* proj[P]; for (int p = 0; p < P; p++) proj[p] = (float*)alloc((size_t)N * D * 4);
    float* xbuf = (float*)alloc((size_t)N * D * 4);
    int*   nbr_idx = (int*)alloc((size_t)P * N * MAXDEG * 4);
    float* nbr_val = (float*)alloc((size_t)P * N * MAXDEG * 4);
    int*   neg_idx = (int*)alloc((size_t)P * N * MAXDEG * 4);
    int*   deg     = (int*)alloc((size_t)P * N * 4);
    char* zero_begin = ws + off;
    float* rowsum = (float*)alloc((size_t)2 * N * 4);
    float* colsum = (float*)alloc((size_t)2 * N * 4);
    float* pdrow  = (float*)alloc((size_t)2 * N * 4);
    float* pdcol  = (float*)alloc((size_t)2 * N * 4);
    float* spacc  = (float*)alloc((size_t)P * D * 4);
    float* beta   = (float*)alloc(16);
    float* loss   = (float*)alloc(16);
    int*   counter = (int*)alloc(16);
    int*   dflag   = (int*)alloc(16);
    size_t zero_bytes = (size_t)((ws + off) - zero_begin);
    hipMemsetAsync(zero_begin, 0, zero_bytes, stream);

    // 0. dtype detection from mps bit patterns (2M words is safe under both dtypes)
    detect_dtype<<<1024, 256, 0, stream>>>((const unsigned int*)mps, 2 * 1024 * 1024, counter);
    finalize_flag<<<1, 1, 0, stream>>>(counter, dflag);

    // 1. sparse extraction of all P adjacencies
    extract_sparse<<<P * N, 256, 0, stream>>>(mps, dflag, nbr_idx, nbr_val, neg_idx, deg);

    dim3 ggrid(N / 64, D / 64);
    // 2. GCN per metapath: X = h @ Wg^T ; emb = prelu(adj @ X + b)
    for (int p = 0; p < P; p++) {
        gemm_ndd<true, 0><<<ggrid, 256, 0, stream>>>(h, W_gcn, (size_t)p * D * D,
                                                     nullptr, 0, dflag, xbuf);
        spmm_prelu<<<N, 256, 0, stream>>>(xbuf, nbr_idx + (size_t)p * N * MAXDEG,
                                          nbr_val + (size_t)p * N * MAXDEG, deg + (size_t)p * N,
                                          b_gcn, (size_t)p * D, prelu_a, p, dflag, emb[p]);
    }
    // 3. attention pre-reduction: spacc[p] = colsum(tanh(emb_p @ Wfc^T + bfc))
    for (int p = 0; p < P; p++) {
        gemm_ndd<false, 2><<<ggrid, 256, 0, stream>>>(emb[p], att_fc_W, 0, att_fc_b, 0, dflag, xbuf);
        colsum_acc<<<16, 256, 0, stream>>>(xbuf, spacc + (size_t)p * D);
    }
    // 4. projections: proj_p = elu(emb_p @ W1^T + b1) @ W2^T + b2, row-normalized
    for (int p = 0; p < P; p++) {
        gemm_ndd<false, 1><<<ggrid, 256, 0, stream>>>(emb[p], proj_W1, 0, proj_b1, 0, dflag, xbuf);
        gemm_ndd<false, 0><<<ggrid, 256, 0, stream>>>(xbuf, proj_W2, 0, proj_b2, 0, dflag, proj[p]);
        rownorm<<<N, 256, 0, stream>>>(proj[p]);
    }
    // 5. two contrast pairs: (q0,q2,mps0) and (q1,q2,mps1)
    for (int pair = 0; pair < 2; pair++) {
        const float* Qa = proj[pair];
        const float* Qb = proj[2];
        int p = pair;
        sim_pair<<<dim3(N / 64, N / 64), 256, 0, stream>>>(Qa, Qb, rowsum + (size_t)pair * N,
                                                           colsum + (size_t)pair * N);
        posdot<<<N, 256, 0, stream>>>(Qa, Qb, nbr_idx + (size_t)p * N * MAXDEG,
                                      nbr_val + (size_t)p * N * MAXDEG, deg + (size_t)p * N,
                                      pdrow + (size_t)pair * N, pdcol + (size_t)pair * N);
        pair_loss<<<N / 256, 256, 0, stream>>>(rowsum + (size_t)pair * N, colsum + (size_t)pair * N,
                                               pdrow + (size_t)pair * N, pdcol + (size_t)pair * N, loss);
    }
    // 6. node losses
    for (int p = 0; p < P; p++) {
        node_loss_k<<<N, 256, 0, stream>>>(emb[p], nbr_idx + (size_t)p * N * MAXDEG,
                                           neg_idx + (size_t)p * N * MAXDEG, deg + (size_t)p * N, loss);
    }
    // 7. attention weights + output
    beta_k<<<1, 256, 0, stream>>>(spacc, att_vec, dflag, beta);
    zmp_out<<<(N * D) / 256, 256, 0, stream>>>(emb[0], emb[1], emb[2], beta, loss, dflag, d_out);
}

// Round 3
// 689.921 us; speedup vs baseline: 2.3011x; 2.3011x over previous
//
#include <hip/hip_runtime.h>
#include <hip/hip_bf16.h>

// Problem constants (Mp_encoder): N nodes, D dims, P metapaths.
constexpr int N = 4096;
constexpr int D = 256;
constexpr int P = 3;
constexpr int MAXDEG = 17;       // K+1
constexpr float TAU = 0.8f;
constexpr float MARGIN = 0.1f;
constexpr float EPS_PD = 1e-6f;

constexpr int LDP = 40;          // LDS k-stride (bf16 elems): 40*2B=80B → 2-way max conflicts

// bf16 conversion-area offsets (elements), all 256-aligned
constexpr int OFF_H    = 0;             // 1048576
constexpr int OFF_WG   = 1048576;       // 196608
constexpr int OFF_ATTW = 1245184;       // 65536
constexpr int OFF_W1   = 1310720;       // 65536
constexpr int OFF_W2   = 1376256;       // 65536
constexpr int OFF_BG   = 1441792;       // 768
constexpr int OFF_ATTB = 1442560;       // 256
constexpr int OFF_AV   = 1442816;       // 256
constexpr int OFF_PA   = 1443072;       // 3 (reserve 256)
constexpr int OFF_B1   = 1443328;       // 256
constexpr int OFF_B2   = 1443584;       // 256
constexpr int CONV_TOTAL = 1443840;

typedef __attribute__((ext_vector_type(8))) short bfrag8;
typedef __attribute__((ext_vector_type(4))) float facc4;

__device__ inline facc4 mfma16(bfrag8 a, bfrag8 b, facc4 c) {
    return __builtin_amdgcn_mfma_f32_16x16x32_bf16(a, b, c, 0, 0, 0);
}
__device__ inline float b2f(__hip_bfloat16 v) { return __bfloat162float(v); }

// Uniform-branch input load: inputs are bf16 or fp32; device flag selects stride.
__device__ inline float load_in(const void* p, size_t i, int bf) {
    return bf ? __bfloat162float(((const __hip_bfloat16*)p)[i])
              : ((const float*)p)[i];
}

// ---------------------------------------------------------------------------
// 0. dtype detection from mps bit patterns
// ---------------------------------------------------------------------------
__global__ void detect_dtype(const unsigned int* __restrict__ w, int nwords,
                             int* __restrict__ counter) {
    int stride = gridDim.x * blockDim.x;
    int c = 0;
    for (int i = blockIdx.x * blockDim.x + threadIdx.x; i < nwords; i += stride) {
        unsigned int x = w[i];
        if ((x & 0xFFFF0000u) == 0u && x != 0u) c++;
    }
    for (int s = 32; s > 0; s >>= 1) c += __shfl_down(c, s);
    if ((threadIdx.x & 63) == 0 && c > 0) atomicAdd(counter, c);
}
__global__ void finalize_flag(const int* __restrict__ counter, int* __restrict__ flag) {
    flag[0] = (counter[0] > 100) ? 1 : 0;
}

// ---------------------------------------------------------------------------
// 1. Convert all dense inputs to a contiguous bf16 staging area.
// ---------------------------------------------------------------------------
__global__ void convert_all(const void* h, const void* wg, const void* attw,
                            const void* w1, const void* w2, const void* bg,
                            const void* attb, const void* av, const void* pa,
                            const void* b1, const void* b2,
                            const int* __restrict__ dflag,
                            __hip_bfloat16* __restrict__ dst) {
    int bf = dflag[0];
    const void* srcs[11] = {h, wg, attw, w1, w2, bg, attb, av, pa, b1, b2};
    const int offs[11] = {OFF_H, OFF_WG, OFF_ATTW, OFF_W1, OFF_W2, OFF_BG,
                          OFF_ATTB, OFF_AV, OFF_PA, OFF_B1, OFF_B2};
    const int lens[11] = {1048576, 196608, 65536, 65536, 65536, 768, 256, 256, 3, 256, 256};
    int stride = gridDim.x * blockDim.x;
    int t0 = blockIdx.x * blockDim.x + threadIdx.x;
    #pragma unroll
    for (int s = 0; s < 11; s++) {
        for (int i = t0; i < lens[s]; i += stride)
            dst[offs[s] + i] = __float2bfloat16(load_in(srcs[s], i, bf));
    }
}

// ---------------------------------------------------------------------------
// 2. Sparse extraction (per (p,n) row of mps)
// ---------------------------------------------------------------------------
__global__ void extract_sparse(const void* __restrict__ mps, const int* __restrict__ dflag,
                               int* __restrict__ nbr_idx, float* __restrict__ nbr_val,
                               int* __restrict__ neg_idx, int* __restrict__ deg) {
    int bf = dflag[0];
    int row = blockIdx.x;              // 0 .. P*N-1
    __shared__ int cnt;
    __shared__ int sidx[32];
    __shared__ float sval[32];
    if (threadIdx.x == 0) cnt = 0;
    __syncthreads();
    for (int c = threadIdx.x; c < N; c += blockDim.x) {
        float v = load_in(mps, (size_t)row * N + c, bf);
        if (v > 0.f) {
            int k = atomicAdd(&cnt, 1);
            if (k < 32) { sidx[k] = c; sval[k] = v; }
        }
    }
    __syncthreads();
    if (threadIdx.x == 0) {
        int dg = cnt; if (dg > MAXDEG) dg = MAXDEG;
        for (int i = 1; i < dg; i++) {           // insertion sort by index
            int ki = sidx[i]; float kv = sval[i]; int j = i - 1;
            while (j >= 0 && sidx[j] > ki) { sidx[j+1] = sidx[j]; sval[j+1] = sval[j]; j--; }
            sidx[j+1] = ki; sval[j+1] = kv;
        }
        deg[row] = dg;
        int* oi = nbr_idx + (size_t)row * MAXDEG;
        float* ov = nbr_val + (size_t)row * MAXDEG;
        int* ng = neg_idx + (size_t)row * MAXDEG;
        for (int i = 0; i < MAXDEG; i++) { oi[i] = (i < dg) ? sidx[i] : 0; ov[i] = (i < dg) ? sval[i] : 0.f; }
        int c = 0, j = 0, found = 0;
        while (found < MAXDEG) {
            if (j < dg && sidx[j] == c) { j++; c++; continue; }
            ng[found++] = c++;
        }
    }
}

// ---------------------------------------------------------------------------
// 3. MFMA GEMM: C[z][r][c] = act( sum_k A[z][r][k]*B[z][c][k] + bias[z][c] )
//    64x64 tile, BK=32, 4 waves of 32x32. A,B,C bf16. Optional colsum epilogue.
//    ACT: 0 none, 1 elu, 2 tanh.
// ---------------------------------------------------------------------------
template <int ACT, bool WRITE, bool COLSUM>
__global__ void gemm_mfma(const __hip_bfloat16* __restrict__ Abase, size_t strideA,
                          const __hip_bfloat16* __restrict__ Bbase, size_t strideB,
                          const __hip_bfloat16* __restrict__ bias, size_t strideBias,
                          __hip_bfloat16* __restrict__ Cbase, size_t strideC,
                          float* __restrict__ csBase, size_t strideCS) {
    int z = blockIdx.z;
    const __hip_bfloat16* A = Abase + (size_t)z * strideA;
    const __hip_bfloat16* B = Bbase + (size_t)z * strideB;
    __shared__ __align__(16) __hip_bfloat16 As[64 * LDP];
    __shared__ __align__(16) __hip_bfloat16 Bs[64 * LDP];
    int bm = blockIdx.x * 64, bn = blockIdx.y * 64;
    int tid = threadIdx.x, wave = tid >> 6, lane = tid & 63;
    int quad = lane >> 4, l15 = lane & 15;
    int wr = (wave & 1) * 32, wc = (wave >> 1) * 32;
    facc4 acc[2][2] = {};
    int sr = tid >> 2, kq = (tid & 3) * 8;
    for (int k0 = 0; k0 < D; k0 += 32) {
        *(bfrag8*)&As[sr * LDP + kq] = *(const bfrag8*)&A[(size_t)(bm + sr) * D + k0 + kq];
        *(bfrag8*)&Bs[sr * LDP + kq] = *(const bfrag8*)&B[(size_t)(bn + sr) * D + k0 + kq];
        __syncthreads();
        bfrag8 af[2], bfr[2];
        #pragma unroll
        for (int mi = 0; mi < 2; mi++)
            af[mi] = *(const bfrag8*)&As[(wr + mi * 16 + l15) * LDP + quad * 8];
        #pragma unroll
        for (int ni = 0; ni < 2; ni++)
            bfr[ni] = *(const bfrag8*)&Bs[(wc + ni * 16 + l15) * LDP + quad * 8];
        #pragma unroll
        for (int mi = 0; mi < 2; mi++)
            #pragma unroll
            for (int ni = 0; ni < 2; ni++)
                acc[mi][ni] = mfma16(af[mi], bfr[ni], acc[mi][ni]);
        __syncthreads();
    }
    float cs[2] = {0.f, 0.f};
    #pragma unroll
    for (int mi = 0; mi < 2; mi++) {
        #pragma unroll
        for (int ni = 0; ni < 2; ni++) {
            int col = bn + wc + ni * 16 + l15;
            #pragma unroll
            for (int r = 0; r < 4; r++) {
                int row = bm + wr + mi * 16 + quad * 4 + r;
                float v = acc[mi][ni][r];
                if (bias) v += b2f(bias[(size_t)z * strideBias + col]);
                if (ACT == 1) v = v > 0.f ? v : expm1f(v);
                if (ACT == 2) v = tanhf(v);
                if (WRITE) Cbase[(size_t)z * strideC + (size_t)row * D + col] = __float2bfloat16(v);
                if (COLSUM) cs[ni] += v;
            }
        }
    }
    if (COLSUM) {
        #pragma unroll
        for (int ni = 0; ni < 2; ni++) {
            float v = cs[ni];
            v += __shfl_xor(v, 16); v += __shfl_xor(v, 32);
            if (quad == 0) {
                int col = bn + wc + ni * 16 + l15;
                atomicAdd(&csBase[(size_t)z * strideCS + col], v);
            }
        }
    }
}

// ---------------------------------------------------------------------------
// 4. spmm + prelu: emb[z][n][d] = prelu( sum_k val_k * X[z][idx_k][d] + bg[z][d] )
// ---------------------------------------------------------------------------
__global__ void spmm_prelu(const __hip_bfloat16* __restrict__ Xbase,
                           const int* __restrict__ nbr_idx, const float* __restrict__ nbr_val,
                           const int* __restrict__ deg, const __hip_bfloat16* __restrict__ conv,
                           __hip_bfloat16* __restrict__ embBase) {
    int z = blockIdx.z, n = blockIdx.x, d = threadIdx.x;
    const __hip_bfloat16* X = Xbase + (size_t)z * N * D;
    const int* idx = nbr_idx + ((size_t)z * N + n) * MAXDEG;
    const float* val = nbr_val + ((size_t)z * N + n) * MAXDEG;
    int dg = deg[z * N + n];
    float acc = 0.f;
    for (int k = 0; k < dg; k++) acc += val[k] * b2f(X[(size_t)idx[k] * D + d]);
    acc += b2f(conv[OFF_BG + z * D + d]);
    float a = b2f(conv[OFF_PA + z]);
    embBase[(size_t)z * N * D + (size_t)n * D + d] = __float2bfloat16(acc > 0.f ? acc : a * acc);
}

// ---------------------------------------------------------------------------
// 5. Row-normalize bf16 in place
// ---------------------------------------------------------------------------
__global__ void rownorm(__hip_bfloat16* __restrict__ qbase) {
    int z = blockIdx.z, n = blockIdx.x, t = threadIdx.x;
    __hip_bfloat16* row = qbase + ((size_t)z * N + n) * D;
    float v = b2f(row[t]);
    __shared__ float red[256];
    red[t] = v * v;
    __syncthreads();
    for (int s = 128; s > 0; s >>= 1) { if (t < s) red[t] += red[t + s]; __syncthreads(); }
    float inv = rsqrtf(red[0] + 1e-30f);
    row[t] = __float2bfloat16(v * inv);
}

// ---------------------------------------------------------------------------
// 6. sim MFMA: per pair z, S = exp(Qz @ Q2^T / TAU) → rowsum/colsum atomics.
//    128x128 tile, 4 waves of 64x64 (16 accs), BK=32.
// ---------------------------------------------------------------------------
__global__ void sim_mfma(const __hip_bfloat16* __restrict__ q,
                         float* __restrict__ rowsum, float* __restrict__ colsum) {
    int pair = blockIdx.z;
    const __hip_bfloat16* Qa = q + (size_t)pair * N * D;
    const __hip_bfloat16* Qb = q + (size_t)2 * N * D;
    __shared__ __align__(16) __hip_bfloat16 As[128 * LDP];
    __shared__ __align__(16) __hip_bfloat16 Bs[128 * LDP];
    int bm = blockIdx.x * 128, bn = blockIdx.y * 128;
    int tid = threadIdx.x, wave = tid >> 6, lane = tid & 63;
    int quad = lane >> 4, l15 = lane & 15;
    int wr = (wave & 1) * 64, wc = (wave >> 1) * 64;
    facc4 acc[4][4] = {};
    int sr = tid >> 2, kq = (tid & 3) * 8;
    for (int k0 = 0; k0 < D; k0 += 32) {
        *(bfrag8*)&As[sr * LDP + kq]        = *(const bfrag8*)&Qa[(size_t)(bm + sr) * D + k0 + kq];
        *(bfrag8*)&As[(sr + 64) * LDP + kq] = *(const bfrag8*)&Qa[(size_t)(bm + sr + 64) * D + k0 + kq];
        *(bfrag8*)&Bs[sr * LDP + kq]        = *(const bfrag8*)&Qb[(size_t)(bn + sr) * D + k0 + kq];
        *(bfrag8*)&Bs[(sr + 64) * LDP + kq] = *(const bfrag8*)&Qb[(size_t)(bn + sr + 64) * D + k0 + kq];
        __syncthreads();
        bfrag8 af[4], bfr[4];
        #pragma unroll
        for (int mi = 0; mi < 4; mi++)
            af[mi] = *(const bfrag8*)&As[(wr + mi * 16 + l15) * LDP + quad * 8];
        #pragma unroll
        for (int ni = 0; ni < 4; ni++)
            bfr[ni] = *(const bfrag8*)&Bs[(wc + ni * 16 + l15) * LDP + quad * 8];
        #pragma unroll
        for (int mi = 0; mi < 4; mi++)
            #pragma unroll
            for (int ni = 0; ni < 4; ni++)
                acc[mi][ni] = mfma16(af[mi], bfr[ni], acc[mi][ni]);
        __syncthreads();
    }
    constexpr float invtau = 1.0f / TAU;
    float rs[4][4];   // [mi][r]
    float cs[4] = {0.f, 0.f, 0.f, 0.f};
    #pragma unroll
    for (int mi = 0; mi < 4; mi++)
        #pragma unroll
        for (int r = 0; r < 4; r++) rs[mi][r] = 0.f;
    #pragma unroll
    for (int mi = 0; mi < 4; mi++)
        #pragma unroll
        for (int ni = 0; ni < 4; ni++)
            #pragma unroll
            for (int r = 0; r < 4; r++) {
                float e = __expf(acc[mi][ni][r] * invtau);
                rs[mi][r] += e;
                cs[ni] += e;
            }
    // row sums: reduce across the 16 lanes of each quad (they hold the 64 cols)
    #pragma unroll
    for (int mi = 0; mi < 4; mi++)
        #pragma unroll
        for (int r = 0; r < 4; r++) {
            float v = rs[mi][r];
            v += __shfl_xor(v, 1); v += __shfl_xor(v, 2);
            v += __shfl_xor(v, 4); v += __shfl_xor(v, 8);
            rs[mi][r] = v;
        }
    if (l15 == 0) {
        #pragma unroll
        for (int mi = 0; mi < 4; mi++)
            #pragma unroll
            for (int r = 0; r < 4; r++)
                atomicAdd(&rowsum[(size_t)pair * N + bm + wr + mi * 16 + quad * 4 + r], rs[mi][r]);
    }
    // col sums: reduce across quads
    #pragma unroll
    for (int ni = 0; ni < 4; ni++) {
        float v = cs[ni];
        v += __shfl_xor(v, 16); v += __shfl_xor(v, 32);
        if (quad == 0)
            atomicAdd(&colsum[(size_t)pair * N + bn + wc + ni * 16 + l15], v);
    }
}

// ---------------------------------------------------------------------------
// 7. pos-weighted sums (bf16 q), batched over pairs via grid.z
// ---------------------------------------------------------------------------
__global__ void posdot(const __hip_bfloat16* __restrict__ q,
                       const int* __restrict__ nbr_idx, const float* __restrict__ nbr_val,
                       const int* __restrict__ deg,
                       float* __restrict__ pdrow, float* __restrict__ pdcol) {
    int pair = blockIdx.z;
    const __hip_bfloat16* Qa = q + (size_t)pair * N * D;
    const __hip_bfloat16* Qb = q + (size_t)2 * N * D;
    int n = blockIdx.x;
    int wv = threadIdx.x >> 6, lane = threadIdx.x & 63;
    int dg = deg[pair * N + n];
    const int* idx = nbr_idx + ((size_t)pair * N + n) * MAXDEG;
    const float* val = nbr_val + ((size_t)pair * N + n) * MAXDEG;
    __shared__ float srow[MAXDEG], scol[MAXDEG];
    const float invtau = 1.0f / TAU;
    for (int k = wv; k < dg; k += 4) {
        int j = idx[k];
        float dr = 0.f, dc = 0.f;
        for (int t = lane; t < D; t += 64) {
            dr += b2f(Qa[(size_t)n * D + t]) * b2f(Qb[(size_t)j * D + t]);
            dc += b2f(Qa[(size_t)j * D + t]) * b2f(Qb[(size_t)n * D + t]);
        }
        for (int s = 32; s > 0; s >>= 1) { dr += __shfl_down(dr, s); dc += __shfl_down(dc, s); }
        if (lane == 0) { srow[k] = __expf(dr * invtau) * val[k]; scol[k] = __expf(dc * invtau) * val[k]; }
    }
    __syncthreads();
    if (threadIdx.x == 0) {
        float sr = 0.f, sc = 0.f;
        for (int k = 0; k < dg; k++) { sr += srow[k]; sc += scol[k]; }
        pdrow[pair * N + n] = sr; pdcol[pair * N + n] = sc;
    }
}

// ---------------------------------------------------------------------------
// 8. pair loss (over both pairs linearly, 2N entries)
// ---------------------------------------------------------------------------
__global__ void pair_loss(const float* __restrict__ rowsum, const float* __restrict__ colsum,
                          const float* __restrict__ pdrow, const float* __restrict__ pdcol,
                          float* __restrict__ loss) {
    int i = blockIdx.x * blockDim.x + threadIdx.x;   // 0..2N-1
    float l12 = -logf(pdrow[i] / (rowsum[i] + 1e-8f));
    float l21 = -logf(pdcol[i] / (colsum[i] + 1e-8f));
    float l = (0.5f * l12 + 0.5f * l21) / (float)N;
    __shared__ float red[256];
    red[threadIdx.x] = l;
    __syncthreads();
    for (int s = 128; s > 0; s >>= 1) { if (threadIdx.x < s) red[threadIdx.x] += red[threadIdx.x + s]; __syncthreads(); }
    if (threadIdx.x == 0) atomicAdd(loss, red[0]);
}

// ---------------------------------------------------------------------------
// 9. node loss (bf16 emb), batched over p via grid.z
// ---------------------------------------------------------------------------
__global__ void node_loss_k(const __hip_bfloat16* __restrict__ embBase,
                            const int* __restrict__ nbr_idx, const int* __restrict__ neg_idx,
                            const int* __restrict__ deg, float* __restrict__ loss) {
    int z = blockIdx.z, n = blockIdx.x;
    const __hip_bfloat16* emb = embBase + (size_t)z * N * D;
    int wv = threadIdx.x >> 6, lane = threadIdx.x & 63;
    int dg = deg[z * N + n];
    __shared__ float per[MAXDEG];
    const __hip_bfloat16* en = emb + (size_t)n * D;
    for (int k = wv; k < dg; k += 4) {
        int jp = nbr_idx[((size_t)z * N + n) * MAXDEG + k];
        int jn = neg_idx[((size_t)z * N + n) * MAXDEG + k];
        const __hip_bfloat16* ep = emb + (size_t)jp * D;
        const __hip_bfloat16* eg = emb + (size_t)jn * D;
        float dp = 0.f, dn = 0.f;
        for (int t = lane; t < D; t += 64) {
            float a = b2f(en[t]);
            float x = a - b2f(ep[t]) + EPS_PD; dp += x * x;
            float y = a - b2f(eg[t]) + EPS_PD; dn += y * y;
        }
        for (int s = 32; s > 0; s >>= 1) { dp += __shfl_down(dp, s); dn += __shfl_down(dn, s); }
        if (lane == 0) { float v = dp - dn + MARGIN; per[k] = v > 0.f ? v : 0.f; }
    }
    __syncthreads();
    if (threadIdx.x == 0) {
        float s = 0.f;
        for (int k = 0; k < dg; k++) s += per[k];
        atomicAdd(loss, s / (float)dg);
    }
}

// ---------------------------------------------------------------------------
// 10. beta softmax
// ---------------------------------------------------------------------------
__global__ void beta_k(const float* __restrict__ spacc, const __hip_bfloat16* __restrict__ conv,
                       float* __restrict__ beta) {
    __shared__ float red[256];
    __shared__ float w[P];
    int t = threadIdx.x;
    for (int p = 0; p < P; p++) {
        float v = (spacc[p * D + t] / (float)N) * b2f(conv[OFF_AV + t]);
        red[t] = v;
        __syncthreads();
        for (int s = 128; s > 0; s >>= 1) { if (t < s) red[t] += red[t + s]; __syncthreads(); }
        if (t == 0) w[p] = red[0];
        __syncthreads();
    }
    if (t == 0) {
        float m = fmaxf(w[0], fmaxf(w[1], w[2]));
        float e0 = __expf(w[0] - m), e1 = __expf(w[1] - m), e2 = __expf(w[2] - m);
        float s = e0 + e1 + e2;
        beta[0] = e0 / s; beta[1] = e1 / s; beta[2] = e2 / s;
    }
}

// ---------------------------------------------------------------------------
// 11. z_mp output + loss scalar (output dtype follows detected input dtype)
// ---------------------------------------------------------------------------
__global__ void zmp_out(const __hip_bfloat16* __restrict__ embBase, const float* __restrict__ beta,
                        const float* __restrict__ loss, const int* __restrict__ dflag,
                        void* __restrict__ out) {
    int bf = dflag[0];
    int i = blockIdx.x * 256 + threadIdx.x;
    float v = beta[0] * b2f(embBase[i]) + beta[1] * b2f(embBase[(size_t)N * D + i]) +
              beta[2] * b2f(embBase[(size_t)2 * N * D + i]);
    if (bf) {
        __hip_bfloat16* o = (__hip_bfloat16*)out;
        o[i] = __float2bfloat16(v);
        if (i == 0) o[(size_t)N * D] = __float2bfloat16(*loss);
    } else {
        float* o = (float*)out;
        o[i] = v;
        if (i == 0) o[(size_t)N * D] = *loss;
    }
}

extern "C" void kernel_launch(void* const* d_in, const int* in_sizes, int n_in,
                              void* d_out, int out_size, void* d_ws, size_t ws_size,
                              hipStream_t stream) {
    const void* h        = d_in[0];
    const void* mps      = d_in[1];
    const void* W_gcn    = d_in[2];
    const void* b_gcn    = d_in[3];
    const void* prelu_a  = d_in[4];
    const void* att_fc_W = d_in[5];
    const void* att_fc_b = d_in[6];
    const void* att_vec  = d_in[7];
    const void* proj_W1  = d_in[8];
    const void* proj_b1  = d_in[9];
    const void* proj_W2  = d_in[10];
    const void* proj_b2  = d_in[11];

    char* ws = (char*)d_ws;
    size_t off = 0;
    auto alloc = [&](size_t bytes) -> char* {
        char* p = ws + off;
        off = (off + bytes + 255) & ~(size_t)255;
        return p;
    };
    __hip_bfloat16* conv = (__hip_bfloat16*)alloc((size_t)CONV_TOTAL * 2);
    __hip_bfloat16* xbuf = (__hip_bfloat16*)alloc((size_t)P * N * D * 2);  // X then reused as elu out
    __hip_bfloat16* emb  = (__hip_bfloat16*)alloc((size_t)P * N * D * 2);
    __hip_bfloat16* q    = (__hip_bfloat16*)alloc((size_t)P * N * D * 2);
    int*   nbr_idx = (int*)alloc((size_t)P * N * MAXDEG * 4);
    float* nbr_val = (float*)alloc((size_t)P * N * MAXDEG * 4);
    int*   neg_idx = (int*)alloc((size_t)P * N * MAXDEG * 4);
    int*   deg     = (int*)alloc((size_t)P * N * 4);
    char* zero_begin = ws + off;
    float* rowsum = (float*)alloc((size_t)2 * N * 4);
    float* colsum = (float*)alloc((size_t)2 * N * 4);
    float* pdrow  = (float*)alloc((size_t)2 * N * 4);
    float* pdcol  = (float*)alloc((size_t)2 * N * 4);
    float* spacc  = (float*)alloc((size_t)P * D * 4);
    float* beta   = (float*)alloc(16);
    float* loss   = (float*)alloc(16);
    int*   counter = (int*)alloc(16);
    int*   dflag   = (int*)alloc(16);
    size_t zero_bytes = (size_t)((ws + off) - zero_begin);
    hipMemsetAsync(zero_begin, 0, zero_bytes, stream);

    // 0. dtype detection
    detect_dtype<<<1024, 256, 0, stream>>>((const unsigned int*)mps, 2 * 1024 * 1024, counter);
    finalize_flag<<<1, 1, 0, stream>>>(counter, dflag);

    // 1. convert dense inputs to bf16 staging
    convert_all<<<512, 256, 0, stream>>>(h, W_gcn, att_fc_W, proj_W1, proj_W2, b_gcn,
                                         att_fc_b, att_vec, prelu_a, proj_b1, proj_b2,
                                         dflag, conv);

    // 2. sparse extraction
    extract_sparse<<<P * N, 256, 0, stream>>>(mps, dflag, nbr_idx, nbr_val, neg_idx, deg);

    dim3 ggrid(N / 64, D / 64, P);
    size_t nd = (size_t)N * D;
    // 3. GCN: X[z] = h @ Wg[z]^T (no bias/act)
    gemm_mfma<0, true, false><<<ggrid, 256, 0, stream>>>(
        conv + OFF_H, 0, conv + OFF_WG, (size_t)D * D, nullptr, 0, xbuf, nd, nullptr, 0);
    // 4. emb[z] = prelu(spmm + bias)
    spmm_prelu<<<dim3(N, 1, P), 256, 0, stream>>>(xbuf, nbr_idx, nbr_val, deg, conv, emb);
    // 5. attention branch: spacc[z][c] = colsum(tanh(emb[z] @ attW^T + attb)) — no C write
    gemm_mfma<2, false, true><<<ggrid, 256, 0, stream>>>(
        emb, nd, conv + OFF_ATTW, 0, conv + OFF_ATTB, 0, nullptr, 0, spacc, (size_t)D);
    // 6. projections: xbuf[z] = elu(emb[z] @ W1^T + b1); q[z] = xbuf[z] @ W2^T + b2
    gemm_mfma<1, true, false><<<ggrid, 256, 0, stream>>>(
        emb, nd, conv + OFF_W1, 0, conv + OFF_B1, 0, xbuf, nd, nullptr, 0);
    gemm_mfma<0, true, false><<<ggrid, 256, 0, stream>>>(
        xbuf, nd, conv + OFF_W2, 0, conv + OFF_B2, 0, q, nd, nullptr, 0);
    // 7. row-normalize q in place
    rownorm<<<dim3(N, 1, P), 256, 0, stream>>>(q);
    // 8. sim (both pairs batched): rowsum/colsum
    sim_mfma<<<dim3(N / 128, N / 128, 2), 256, 0, stream>>>(q, rowsum, colsum);
    // 9. pos-weighted sums
    posdot<<<dim3(N, 1, 2), 256, 0, stream>>>(q, nbr_idx, nbr_val, deg, pdrow, pdcol);
    // 10. pair losses
    pair_loss<<<(2 * N) / 256, 256, 0, stream>>>(rowsum, colsum, pdrow, pdcol, loss);
    // 11. node losses
    node_loss_k<<<dim3(N, 1, P), 256, 0, stream>>>(emb, nbr_idx, neg_idx, deg, loss);
    // 12. attention weights + output
    beta_k<<<1, 256, 0, stream>>>(spacc, conv, beta);
    zmp_out<<<(N * D) / 256, 256, 0, stream>>>(emb, beta, loss, dflag, d_out);
}

// Round 4
// 542.735 us; speedup vs baseline: 2.9252x; 1.2712x over previous
//
#include <hip/hip_runtime.h>
#include <hip/hip_bf16.h>

// Problem constants (Mp_encoder): N nodes, D dims, P metapaths.
constexpr int N = 4096;
constexpr int D = 256;
constexpr int P = 3;
constexpr int MAXDEG = 17;       // K+1
constexpr float TAU = 0.8f;
constexpr float MARGIN = 0.1f;
constexpr float EPS_PD = 1e-6f;

constexpr int LDP = 40;          // LDS k-stride (bf16 elems): 40*2B=80B → 2-way max conflicts

// bf16 conversion-area offsets (elements), all 256-aligned
constexpr int OFF_H    = 0;             // 1048576
constexpr int OFF_WG   = 1048576;       // 196608
constexpr int OFF_ATTW = 1245184;       // 65536
constexpr int OFF_W1   = 1310720;       // 65536
constexpr int OFF_W2   = 1376256;       // 65536
constexpr int OFF_BG   = 1441792;       // 768
constexpr int OFF_ATTB = 1442560;       // 256
constexpr int OFF_AV   = 1442816;       // 256
constexpr int OFF_PA   = 1443072;       // 3 (reserve 256)
constexpr int OFF_B1   = 1443328;       // 256
constexpr int OFF_B2   = 1443584;       // 256
constexpr int CONV_TOTAL = 1443840;

typedef __attribute__((ext_vector_type(8))) short bfrag8;
typedef __attribute__((ext_vector_type(4))) float facc4;

__device__ inline facc4 mfma16(bfrag8 a, bfrag8 b, facc4 c) {
    return __builtin_amdgcn_mfma_f32_16x16x32_bf16(a, b, c, 0, 0, 0);
}
__device__ inline float b2f(__hip_bfloat16 v) { return __bfloat162float(v); }
__device__ inline float bfbits2f(unsigned short u) {
    return __uint_as_float(((unsigned int)u) << 16);
}

// Uniform-branch input load: inputs are bf16 or fp32; device flag selects stride.
__device__ inline float load_in(const void* p, size_t i, int bf) {
    return bf ? __bfloat162float(((const __hip_bfloat16*)p)[i])
              : ((const float*)p)[i];
}

// ---------------------------------------------------------------------------
// 0. dtype detection from mps bit patterns
// ---------------------------------------------------------------------------
__global__ void detect_dtype(const unsigned int* __restrict__ w, int nwords,
                             int* __restrict__ counter) {
    int stride = gridDim.x * blockDim.x;
    int c = 0;
    for (int i = blockIdx.x * blockDim.x + threadIdx.x; i < nwords; i += stride) {
        unsigned int x = w[i];
        if ((x & 0xFFFF0000u) == 0u && x != 0u) c++;
    }
    for (int s = 32; s > 0; s >>= 1) c += __shfl_down(c, s);
    if ((threadIdx.x & 63) == 0 && c > 0) atomicAdd(counter, c);
}
__global__ void finalize_flag(const int* __restrict__ counter, int* __restrict__ flag) {
    flag[0] = (counter[0] > 100) ? 1 : 0;
}

// ---------------------------------------------------------------------------
// 1. Convert all dense inputs to a contiguous bf16 staging area.
// ---------------------------------------------------------------------------
__global__ void convert_all(const void* h, const void* wg, const void* attw,
                            const void* w1, const void* w2, const void* bg,
                            const void* attb, const void* av, const void* pa,
                            const void* b1, const void* b2,
                            const int* __restrict__ dflag,
                            __hip_bfloat16* __restrict__ dst) {
    int bf = dflag[0];
    const void* srcs[11] = {h, wg, attw, w1, w2, bg, attb, av, pa, b1, b2};
    const int offs[11] = {OFF_H, OFF_WG, OFF_ATTW, OFF_W1, OFF_W2, OFF_BG,
                          OFF_ATTB, OFF_AV, OFF_PA, OFF_B1, OFF_B2};
    const int lens[11] = {1048576, 196608, 65536, 65536, 65536, 768, 256, 256, 3, 256, 256};
    int stride = gridDim.x * blockDim.x;
    int t0 = blockIdx.x * blockDim.x + threadIdx.x;
    #pragma unroll
    for (int s = 0; s < 11; s++) {
        for (int i = t0; i < lens[s]; i += stride)
            dst[offs[s] + i] = __float2bfloat16(load_in(srcs[s], i, bf));
    }
}

// ---------------------------------------------------------------------------
// 2. Sparse extraction (per (p,n) row of mps), vectorized 16B loads.
// ---------------------------------------------------------------------------
__global__ void extract_sparse(const void* __restrict__ mps, const int* __restrict__ dflag,
                               int* __restrict__ nbr_idx, float* __restrict__ nbr_val,
                               int* __restrict__ neg_idx, int* __restrict__ deg) {
    int bf = dflag[0];
    int row = blockIdx.x;              // 0 .. P*N-1
    int t = threadIdx.x;               // 256 threads, 16 elems each
    __shared__ int cnt;
    __shared__ int sidx[32];
    __shared__ float sval[32];
    if (t == 0) cnt = 0;
    __syncthreads();
    int e0 = t * 16;
    if (bf) {
        const uint4* base = (const uint4*)((const __hip_bfloat16*)mps + (size_t)row * N + e0);
        #pragma unroll
        for (int v = 0; v < 2; v++) {
            uint4 w = base[v];
            unsigned int ws[4] = {w.x, w.y, w.z, w.w};
            #pragma unroll
            for (int j = 0; j < 4; j++) {
                unsigned short lo = (unsigned short)(ws[j] & 0xFFFFu);
                unsigned short hi = (unsigned short)(ws[j] >> 16);
                if (lo) { int k = atomicAdd(&cnt, 1); if (k < 32) { sidx[k] = e0 + v * 8 + j * 2;     sval[k] = bfbits2f(lo); } }
                if (hi) { int k = atomicAdd(&cnt, 1); if (k < 32) { sidx[k] = e0 + v * 8 + j * 2 + 1; sval[k] = bfbits2f(hi); } }
            }
        }
    } else {
        const float4* base = (const float4*)((const float*)mps + (size_t)row * N + e0);
        #pragma unroll
        for (int v = 0; v < 4; v++) {
            float4 w = base[v];
            float ws[4] = {w.x, w.y, w.z, w.w};
            #pragma unroll
            for (int j = 0; j < 4; j++)
                if (ws[j] > 0.f) { int k = atomicAdd(&cnt, 1); if (k < 32) { sidx[k] = e0 + v * 4 + j; sval[k] = ws[j]; } }
        }
    }
    __syncthreads();
    if (t == 0) {
        int dg = cnt; if (dg > MAXDEG) dg = MAXDEG;
        for (int i = 1; i < dg; i++) {           // insertion sort by index
            int ki = sidx[i]; float kv = sval[i]; int j = i - 1;
            while (j >= 0 && sidx[j] > ki) { sidx[j+1] = sidx[j]; sval[j+1] = sval[j]; j--; }
            sidx[j+1] = ki; sval[j+1] = kv;
        }
        deg[row] = dg;
        int* oi = nbr_idx + (size_t)row * MAXDEG;
        float* ov = nbr_val + (size_t)row * MAXDEG;
        int* ng = neg_idx + (size_t)row * MAXDEG;
        for (int i = 0; i < MAXDEG; i++) { oi[i] = (i < dg) ? sidx[i] : 0; ov[i] = (i < dg) ? sval[i] : 0.f; }
        int c = 0, j = 0, found = 0;
        while (found < MAXDEG) {
            if (j < dg && sidx[j] == c) { j++; c++; continue; }
            ng[found++] = c++;
        }
    }
}

// ---------------------------------------------------------------------------
// 3. MFMA GEMM: C[z][r][c] = act( sum_k A[z][r][k]*B[z][c][k] + bias[z][c] )
//    64x64 tile, BK=32, 4 waves of 32x32. A,B,C bf16. Optional colsum epilogue.
// ---------------------------------------------------------------------------
template <int ACT, bool WRITE, bool COLSUM>
__global__ void gemm_mfma(const __hip_bfloat16* __restrict__ Abase, size_t strideA,
                          const __hip_bfloat16* __restrict__ Bbase, size_t strideB,
                          const __hip_bfloat16* __restrict__ bias, size_t strideBias,
                          __hip_bfloat16* __restrict__ Cbase, size_t strideC,
                          float* __restrict__ csBase, size_t strideCS) {
    int z = blockIdx.z;
    const __hip_bfloat16* A = Abase + (size_t)z * strideA;
    const __hip_bfloat16* B = Bbase + (size_t)z * strideB;
    __shared__ __align__(16) __hip_bfloat16 As[64 * LDP];
    __shared__ __align__(16) __hip_bfloat16 Bs[64 * LDP];
    int bm = blockIdx.x * 64, bn = blockIdx.y * 64;
    int tid = threadIdx.x, wave = tid >> 6, lane = tid & 63;
    int quad = lane >> 4, l15 = lane & 15;
    int wr = (wave & 1) * 32, wc = (wave >> 1) * 32;
    facc4 acc[2][2] = {};
    int sr = tid >> 2, kq = (tid & 3) * 8;
    for (int k0 = 0; k0 < D; k0 += 32) {
        *(bfrag8*)&As[sr * LDP + kq] = *(const bfrag8*)&A[(size_t)(bm + sr) * D + k0 + kq];
        *(bfrag8*)&Bs[sr * LDP + kq] = *(const bfrag8*)&B[(size_t)(bn + sr) * D + k0 + kq];
        __syncthreads();
        bfrag8 af[2], bfr[2];
        #pragma unroll
        for (int mi = 0; mi < 2; mi++)
            af[mi] = *(const bfrag8*)&As[(wr + mi * 16 + l15) * LDP + quad * 8];
        #pragma unroll
        for (int ni = 0; ni < 2; ni++)
            bfr[ni] = *(const bfrag8*)&Bs[(wc + ni * 16 + l15) * LDP + quad * 8];
        #pragma unroll
        for (int mi = 0; mi < 2; mi++)
            #pragma unroll
            for (int ni = 0; ni < 2; ni++)
                acc[mi][ni] = mfma16(af[mi], bfr[ni], acc[mi][ni]);
        __syncthreads();
    }
    float cs[2] = {0.f, 0.f};
    #pragma unroll
    for (int mi = 0; mi < 2; mi++) {
        #pragma unroll
        for (int ni = 0; ni < 2; ni++) {
            int col = bn + wc + ni * 16 + l15;
            #pragma unroll
            for (int r = 0; r < 4; r++) {
                int row = bm + wr + mi * 16 + quad * 4 + r;
                float v = acc[mi][ni][r];
                if (bias) v += b2f(bias[(size_t)z * strideBias + col]);
                if (ACT == 1) v = v > 0.f ? v : expm1f(v);
                if (ACT == 2) v = tanhf(v);
                if (WRITE) Cbase[(size_t)z * strideC + (size_t)row * D + col] = __float2bfloat16(v);
                if (COLSUM) cs[ni] += v;
            }
        }
    }
    if (COLSUM) {
        #pragma unroll
        for (int ni = 0; ni < 2; ni++) {
            float v = cs[ni];
            v += __shfl_xor(v, 16); v += __shfl_xor(v, 32);
            if (quad == 0) {
                int col = bn + wc + ni * 16 + l15;
                atomicAdd(&csBase[(size_t)z * strideCS + col], v);
            }
        }
    }
}

// ---------------------------------------------------------------------------
// 4. spmm + prelu: emb[z][n][d] = prelu( sum_k val_k * X[z][idx_k][d] + bg[z][d] )
// ---------------------------------------------------------------------------
__global__ void spmm_prelu(const __hip_bfloat16* __restrict__ Xbase,
                           const int* __restrict__ nbr_idx, const float* __restrict__ nbr_val,
                           const int* __restrict__ deg, const __hip_bfloat16* __restrict__ conv,
                           __hip_bfloat16* __restrict__ embBase) {
    int z = blockIdx.z, n = blockIdx.x, d = threadIdx.x;
    const __hip_bfloat16* X = Xbase + (size_t)z * N * D;
    const int* idx = nbr_idx + ((size_t)z * N + n) * MAXDEG;
    const float* val = nbr_val + ((size_t)z * N + n) * MAXDEG;
    int dg = deg[z * N + n];
    float acc = 0.f;
    for (int k = 0; k < dg; k++) acc += val[k] * b2f(X[(size_t)idx[k] * D + d]);
    acc += b2f(conv[OFF_BG + z * D + d]);
    float a = b2f(conv[OFF_PA + z]);
    embBase[(size_t)z * N * D + (size_t)n * D + d] = __float2bfloat16(acc > 0.f ? acc : a * acc);
}

// ---------------------------------------------------------------------------
// 5. Row-normalize bf16 in place
// ---------------------------------------------------------------------------
__global__ void rownorm(__hip_bfloat16* __restrict__ qbase) {
    int z = blockIdx.z, n = blockIdx.x, t = threadIdx.x;
    __hip_bfloat16* row = qbase + ((size_t)z * N + n) * D;
    float v = b2f(row[t]);
    __shared__ float red[256];
    red[t] = v * v;
    __syncthreads();
    for (int s = 128; s > 0; s >>= 1) { if (t < s) red[t] += red[t + s]; __syncthreads(); }
    float inv = rsqrtf(red[0] + 1e-30f);
    row[t] = __float2bfloat16(v * inv);
}

// ---------------------------------------------------------------------------
// 6. sim MFMA: per pair z, S = exp(Qz @ Q2^T / TAU) → rowsum/colsum atomics.
//    128x128 tile, 4 waves of 64x64 (16 accs), BK=32.
// ---------------------------------------------------------------------------
__global__ void sim_mfma(const __hip_bfloat16* __restrict__ q,
                         float* __restrict__ rowsum, float* __restrict__ colsum) {
    int pair = blockIdx.z;
    const __hip_bfloat16* Qa = q + (size_t)pair * N * D;
    const __hip_bfloat16* Qb = q + (size_t)2 * N * D;
    __shared__ __align__(16) __hip_bfloat16 As[128 * LDP];
    __shared__ __align__(16) __hip_bfloat16 Bs[128 * LDP];
    int bm = blockIdx.x * 128, bn = blockIdx.y * 128;
    int tid = threadIdx.x, wave = tid >> 6, lane = tid & 63;
    int quad = lane >> 4, l15 = lane & 15;
    int wr = (wave & 1) * 64, wc = (wave >> 1) * 64;
    facc4 acc[4][4] = {};
    int sr = tid >> 2, kq = (tid & 3) * 8;
    for (int k0 = 0; k0 < D; k0 += 32) {
        *(bfrag8*)&As[sr * LDP + kq]        = *(const bfrag8*)&Qa[(size_t)(bm + sr) * D + k0 + kq];
        *(bfrag8*)&As[(sr + 64) * LDP + kq] = *(const bfrag8*)&Qa[(size_t)(bm + sr + 64) * D + k0 + kq];
        *(bfrag8*)&Bs[sr * LDP + kq]        = *(const bfrag8*)&Qb[(size_t)(bn + sr) * D + k0 + kq];
        *(bfrag8*)&Bs[(sr + 64) * LDP + kq] = *(const bfrag8*)&Qb[(size_t)(bn + sr + 64) * D + k0 + kq];
        __syncthreads();
        bfrag8 af[4], bfr[4];
        #pragma unroll
        for (int mi = 0; mi < 4; mi++)
            af[mi] = *(const bfrag8*)&As[(wr + mi * 16 + l15) * LDP + quad * 8];
        #pragma unroll
        for (int ni = 0; ni < 4; ni++)
            bfr[ni] = *(const bfrag8*)&Bs[(wc + ni * 16 + l15) * LDP + quad * 8];
        #pragma unroll
        for (int mi = 0; mi < 4; mi++)
            #pragma unroll
            for (int ni = 0; ni < 4; ni++)
                acc[mi][ni] = mfma16(af[mi], bfr[ni], acc[mi][ni]);
        __syncthreads();
    }
    constexpr float invtau = 1.0f / TAU;
    float rs[4][4];   // [mi][r]
    float cs[4] = {0.f, 0.f, 0.f, 0.f};
    #pragma unroll
    for (int mi = 0; mi < 4; mi++)
        #pragma unroll
        for (int r = 0; r < 4; r++) rs[mi][r] = 0.f;
    #pragma unroll
    for (int mi = 0; mi < 4; mi++)
        #pragma unroll
        for (int ni = 0; ni < 4; ni++)
            #pragma unroll
            for (int r = 0; r < 4; r++) {
                float e = __expf(acc[mi][ni][r] * invtau);
                rs[mi][r] += e;
                cs[ni] += e;
            }
    #pragma unroll
    for (int mi = 0; mi < 4; mi++)
        #pragma unroll
        for (int r = 0; r < 4; r++) {
            float v = rs[mi][r];
            v += __shfl_xor(v, 1); v += __shfl_xor(v, 2);
            v += __shfl_xor(v, 4); v += __shfl_xor(v, 8);
            rs[mi][r] = v;
        }
    if (l15 == 0) {
        #pragma unroll
        for (int mi = 0; mi < 4; mi++)
            #pragma unroll
            for (int r = 0; r < 4; r++)
                atomicAdd(&rowsum[(size_t)pair * N + bm + wr + mi * 16 + quad * 4 + r], rs[mi][r]);
    }
    #pragma unroll
    for (int ni = 0; ni < 4; ni++) {
        float v = cs[ni];
        v += __shfl_xor(v, 16); v += __shfl_xor(v, 32);
        if (quad == 0)
            atomicAdd(&colsum[(size_t)pair * N + bn + wc + ni * 16 + l15], v);
    }
}

// ---------------------------------------------------------------------------
// 7. pos-weighted sums, one wave per node, vector loads.
// ---------------------------------------------------------------------------
__global__ void posdot(const __hip_bfloat16* __restrict__ q,
                       const int* __restrict__ nbr_idx, const float* __restrict__ nbr_val,
                       const int* __restrict__ deg,
                       float* __restrict__ pdrow, float* __restrict__ pdcol) {
    int pair = blockIdx.z;
    int wave = threadIdx.x >> 6, lane = threadIdx.x & 63;
    int n = blockIdx.x * 4 + wave;
    const __hip_bfloat16* Qa = q + (size_t)pair * N * D;
    const __hip_bfloat16* Qb = q + (size_t)2 * N * D;
    int dg = deg[pair * N + n];
    const int* idx = nbr_idx + ((size_t)pair * N + n) * MAXDEG;
    const float* val = nbr_val + ((size_t)pair * N + n) * MAXDEG;
    const float invtau = 1.0f / TAU;
    // anchor rows: 4 contiguous bf16 per lane
    ushort4 ar = *(const ushort4*)&Qa[(size_t)n * D + lane * 4];
    ushort4 br = *(const ushort4*)&Qb[(size_t)n * D + lane * 4];
    float a[4] = {bfbits2f(ar.x), bfbits2f(ar.y), bfbits2f(ar.z), bfbits2f(ar.w)};
    float b[4] = {bfbits2f(br.x), bfbits2f(br.y), bfbits2f(br.z), bfbits2f(br.w)};
    float sr = 0.f, sc = 0.f;
    for (int k = 0; k < dg; k++) {
        int j = idx[k];
        ushort4 pj = *(const ushort4*)&Qb[(size_t)j * D + lane * 4];
        ushort4 aj = *(const ushort4*)&Qa[(size_t)j * D + lane * 4];
        float dr = a[0] * bfbits2f(pj.x) + a[1] * bfbits2f(pj.y) +
                   a[2] * bfbits2f(pj.z) + a[3] * bfbits2f(pj.w);
        float dc = b[0] * bfbits2f(aj.x) + b[1] * bfbits2f(aj.y) +
                   b[2] * bfbits2f(aj.z) + b[3] * bfbits2f(aj.w);
        #pragma unroll
        for (int s = 1; s <= 32; s <<= 1) { dr += __shfl_xor(dr, s); dc += __shfl_xor(dc, s); }
        sr += __expf(dr * invtau) * val[k];
        sc += __expf(dc * invtau) * val[k];
    }
    if (lane == 0) { pdrow[pair * N + n] = sr; pdcol[pair * N + n] = sc; }
}

// ---------------------------------------------------------------------------
// 8. node loss: one wave per node, partials to buffer (no atomics).
// ---------------------------------------------------------------------------
__global__ void node_loss_k(const __hip_bfloat16* __restrict__ embBase,
                            const int* __restrict__ nbr_idx, const int* __restrict__ neg_idx,
                            const int* __restrict__ deg, float* __restrict__ nlpart) {
    int z = blockIdx.z;
    int wave = threadIdx.x >> 6, lane = threadIdx.x & 63;
    int n = blockIdx.x * 4 + wave;
    const __hip_bfloat16* emb = embBase + (size_t)z * N * D;
    int dg = deg[z * N + n];
    const int* ip = nbr_idx + ((size_t)z * N + n) * MAXDEG;
    const int* ig = neg_idx + ((size_t)z * N + n) * MAXDEG;
    ushort4 ar = *(const ushort4*)&emb[(size_t)n * D + lane * 4];
    float a[4] = {bfbits2f(ar.x), bfbits2f(ar.y), bfbits2f(ar.z), bfbits2f(ar.w)};
    float s = 0.f;
    for (int k = 0; k < dg; k++) {
        int jp = ip[k], jn = ig[k];
        ushort4 pr = *(const ushort4*)&emb[(size_t)jp * D + lane * 4];
        ushort4 nr = *(const ushort4*)&emb[(size_t)jn * D + lane * 4];
        float pv[4] = {bfbits2f(pr.x), bfbits2f(pr.y), bfbits2f(pr.z), bfbits2f(pr.w)};
        float nv[4] = {bfbits2f(nr.x), bfbits2f(nr.y), bfbits2f(nr.z), bfbits2f(nr.w)};
        float dp = 0.f, dn = 0.f;
        #pragma unroll
        for (int i = 0; i < 4; i++) {
            float x = a[i] - pv[i] + EPS_PD; dp += x * x;
            float y = a[i] - nv[i] + EPS_PD; dn += y * y;
        }
        #pragma unroll
        for (int st = 1; st <= 32; st <<= 1) { dp += __shfl_xor(dp, st); dn += __shfl_xor(dn, st); }
        float v = dp - dn + MARGIN;
        s += v > 0.f ? v : 0.f;
    }
    if (lane == 0) nlpart[z * N + n] = s / (float)dg;
}

// ---------------------------------------------------------------------------
// 9. final loss reduce: node partials + pair log-terms, single block, no atomics
// ---------------------------------------------------------------------------
__global__ void reduce_loss(const float* __restrict__ nlpart,
                            const float* __restrict__ rowsum, const float* __restrict__ colsum,
                            const float* __restrict__ pdrow, const float* __restrict__ pdcol,
                            float* __restrict__ loss) {
    int t = threadIdx.x;
    float s = 0.f;
    for (int i = t; i < P * N; i += 256) s += nlpart[i];
    for (int i = t; i < 2 * N; i += 256) {
        float l12 = -logf(pdrow[i] / (rowsum[i] + 1e-8f));
        float l21 = -logf(pdcol[i] / (colsum[i] + 1e-8f));
        s += (0.5f * l12 + 0.5f * l21) / (float)N;
    }
    __shared__ float red[256];
    red[t] = s;
    __syncthreads();
    for (int st = 128; st > 0; st >>= 1) { if (t < st) red[t] += red[t + st]; __syncthreads(); }
    if (t == 0) loss[0] = red[0];
}

// ---------------------------------------------------------------------------
// 10. beta softmax
// ---------------------------------------------------------------------------
__global__ void beta_k(const float* __restrict__ spacc, const __hip_bfloat16* __restrict__ conv,
                       float* __restrict__ beta) {
    __shared__ float red[256];
    __shared__ float w[P];
    int t = threadIdx.x;
    for (int p = 0; p < P; p++) {
        float v = (spacc[p * D + t] / (float)N) * b2f(conv[OFF_AV + t]);
        red[t] = v;
        __syncthreads();
        for (int s = 128; s > 0; s >>= 1) { if (t < s) red[t] += red[t + s]; __syncthreads(); }
        if (t == 0) w[p] = red[0];
        __syncthreads();
    }
    if (t == 0) {
        float m = fmaxf(w[0], fmaxf(w[1], w[2]));
        float e0 = __expf(w[0] - m), e1 = __expf(w[1] - m), e2 = __expf(w[2] - m);
        float s = e0 + e1 + e2;
        beta[0] = e0 / s; beta[1] = e1 / s; beta[2] = e2 / s;
    }
}

// ---------------------------------------------------------------------------
// 11. z_mp output + loss scalar (output dtype follows detected input dtype)
// ---------------------------------------------------------------------------
__global__ void zmp_out(const __hip_bfloat16* __restrict__ embBase, const float* __restrict__ beta,
                        const float* __restrict__ loss, const int* __restrict__ dflag,
                        void* __restrict__ out) {
    int bf = dflag[0];
    int i = blockIdx.x * 256 + threadIdx.x;
    float v = beta[0] * b2f(embBase[i]) + beta[1] * b2f(embBase[(size_t)N * D + i]) +
              beta[2] * b2f(embBase[(size_t)2 * N * D + i]);
    if (bf) {
        __hip_bfloat16* o = (__hip_bfloat16*)out;
        o[i] = __float2bfloat16(v);
        if (i == 0) o[(size_t)N * D] = __float2bfloat16(*loss);
    } else {
        float* o = (float*)out;
        o[i] = v;
        if (i == 0) o[(size_t)N * D] = *loss;
    }
}

extern "C" void kernel_launch(void* const* d_in, const int* in_sizes, int n_in,
                              void* d_out, int out_size, void* d_ws, size_t ws_size,
                              hipStream_t stream) {
    const void* h        = d_in[0];
    const void* mps      = d_in[1];
    const void* W_gcn    = d_in[2];
    const void* b_gcn    = d_in[3];
    const void* prelu_a  = d_in[4];
    const void* att_fc_W = d_in[5];
    const void* att_fc_b = d_in[6];
    const void* att_vec  = d_in[7];
    const void* proj_W1  = d_in[8];
    const void* proj_b1  = d_in[9];
    const void* proj_W2  = d_in[10];
    const void* proj_b2  = d_in[11];

    char* ws = (char*)d_ws;
    size_t off = 0;
    auto alloc = [&](size_t bytes) -> char* {
        char* p = ws + off;
        off = (off + bytes + 255) & ~(size_t)255;
        return p;
    };
    __hip_bfloat16* conv = (__hip_bfloat16*)alloc((size_t)CONV_TOTAL * 2);
    __hip_bfloat16* xbuf = (__hip_bfloat16*)alloc((size_t)P * N * D * 2);
    __hip_bfloat16* emb  = (__hip_bfloat16*)alloc((size_t)P * N * D * 2);
    __hip_bfloat16* q    = (__hip_bfloat16*)alloc((size_t)P * N * D * 2);
    int*   nbr_idx = (int*)alloc((size_t)P * N * MAXDEG * 4);
    float* nbr_val = (float*)alloc((size_t)P * N * MAXDEG * 4);
    int*   neg_idx = (int*)alloc((size_t)P * N * MAXDEG * 4);
    int*   deg     = (int*)alloc((size_t)P * N * 4);
    float* nlpart  = (float*)alloc((size_t)P * N * 4);
    float* pdrow   = (float*)alloc((size_t)2 * N * 4);
    float* pdcol   = (float*)alloc((size_t)2 * N * 4);
    char* zero_begin = ws + off;
    float* rowsum = (float*)alloc((size_t)2 * N * 4);
    float* colsum = (float*)alloc((size_t)2 * N * 4);
    float* spacc  = (float*)alloc((size_t)P * D * 4);
    float* beta   = (float*)alloc(16);
    float* loss   = (float*)alloc(16);
    int*   counter = (int*)alloc(16);
    int*   dflag   = (int*)alloc(16);
    size_t zero_bytes = (size_t)((ws + off) - zero_begin);
    hipMemsetAsync(zero_begin, 0, zero_bytes, stream);

    // 0. dtype detection
    detect_dtype<<<1024, 256, 0, stream>>>((const unsigned int*)mps, 2 * 1024 * 1024, counter);
    finalize_flag<<<1, 1, 0, stream>>>(counter, dflag);

    // 1. convert dense inputs to bf16 staging
    convert_all<<<512, 256, 0, stream>>>(h, W_gcn, att_fc_W, proj_W1, proj_W2, b_gcn,
                                         att_fc_b, att_vec, prelu_a, proj_b1, proj_b2,
                                         dflag, conv);

    // 2. sparse extraction
    extract_sparse<<<P * N, 256, 0, stream>>>(mps, dflag, nbr_idx, nbr_val, neg_idx, deg);

    dim3 ggrid(N / 64, D / 64, P);
    size_t nd = (size_t)N * D;
    // 3. GCN: X[z] = h @ Wg[z]^T
    gemm_mfma<0, true, false><<<ggrid, 256, 0, stream>>>(
        conv + OFF_H, 0, conv + OFF_WG, (size_t)D * D, nullptr, 0, xbuf, nd, nullptr, 0);
    // 4. emb[z] = prelu(spmm + bias)
    spmm_prelu<<<dim3(N, 1, P), 256, 0, stream>>>(xbuf, nbr_idx, nbr_val, deg, conv, emb);
    // 5. attention branch: spacc[z][c] = colsum(tanh(emb[z] @ attW^T + attb))
    gemm_mfma<2, false, true><<<ggrid, 256, 0, stream>>>(
        emb, nd, conv + OFF_ATTW, 0, conv + OFF_ATTB, 0, nullptr, 0, spacc, (size_t)D);
    // 6. projections
    gemm_mfma<1, true, false><<<ggrid, 256, 0, stream>>>(
        emb, nd, conv + OFF_W1, 0, conv + OFF_B1, 0, xbuf, nd, nullptr, 0);
    gemm_mfma<0, true, false><<<ggrid, 256, 0, stream>>>(
        xbuf, nd, conv + OFF_W2, 0, conv + OFF_B2, 0, q, nd, nullptr, 0);
    // 7. row-normalize q in place
    rownorm<<<dim3(N, 1, P), 256, 0, stream>>>(q);
    // 8. sim (both pairs batched): rowsum/colsum
    sim_mfma<<<dim3(N / 128, N / 128, 2), 256, 0, stream>>>(q, rowsum, colsum);
    // 9. pos-weighted sums (wave per node)
    posdot<<<dim3(N / 4, 1, 2), 256, 0, stream>>>(q, nbr_idx, nbr_val, deg, pdrow, pdcol);
    // 10. node losses (wave per node, partials)
    node_loss_k<<<dim3(N / 4, 1, P), 256, 0, stream>>>(emb, nbr_idx, neg_idx, deg, nlpart);
    // 11. final loss reduce (no atomics)
    reduce_loss<<<1, 256, 0, stream>>>(nlpart, rowsum, colsum, pdrow, pdcol, loss);
    // 12. attention weights + output
    beta_k<<<1, 256, 0, stream>>>(spacc, conv, beta);
    zmp_out<<<(N * D) / 256, 256, 0, stream>>>(emb, beta, loss, dflag, d_out);
}

// Round 5
// 510.441 us; speedup vs baseline: 3.1103x; 1.0633x over previous
//
#include <hip/hip_runtime.h>
#include <hip/hip_bf16.h>

// Problem constants (Mp_encoder): N nodes, D dims, P metapaths.
constexpr int N = 4096;
constexpr int D = 256;
constexpr int P = 3;
constexpr int MAXDEG = 17;       // K+1
constexpr float TAU = 0.8f;
constexpr float MARGIN = 0.1f;
constexpr float EPS_PD = 1e-6f;

constexpr int LDP = 40;          // LDS k-stride for 64-tiles (2-way max conflicts)
constexpr int LDK = 72;          // LDS k-stride for sim BK=64 staging

// bf16 conversion-area offsets (elements), all 256-aligned
constexpr int OFF_H    = 0;             // 1048576
constexpr int OFF_WG   = 1048576;       // 196608
constexpr int OFF_ATTW = 1245184;       // 65536
constexpr int OFF_W1   = 1310720;       // 65536
constexpr int OFF_W2   = 1376256;       // 65536
constexpr int OFF_BG   = 1441792;       // 768
constexpr int OFF_ATTB = 1442560;       // 256
constexpr int OFF_AV   = 1442816;       // 256
constexpr int OFF_PA   = 1443072;       // 3 (reserve 256)
constexpr int OFF_B1   = 1443328;       // 256
constexpr int OFF_B2   = 1443584;       // 256
constexpr int CONV_TOTAL = 1443840;

typedef __attribute__((ext_vector_type(8))) short bfrag8;
typedef __attribute__((ext_vector_type(4))) float facc4;

__device__ inline facc4 mfma16(bfrag8 a, bfrag8 b, facc4 c) {
    return __builtin_amdgcn_mfma_f32_16x16x32_bf16(a, b, c, 0, 0, 0);
}
__device__ inline float b2f(__hip_bfloat16 v) { return __bfloat162float(v); }
__device__ inline float bfbits2f(unsigned short u) {
    return __uint_as_float(((unsigned int)u) << 16);
}
__device__ inline unsigned short f2bfbits(float v) {
    __hip_bfloat16 t = __float2bfloat16(v);
    return *(unsigned short*)&t;
}
__device__ inline int get_bf(const int* __restrict__ counter) { return counter[0] > 100; }

// Uniform-branch input load: inputs are bf16 or fp32; detected flag selects stride.
__device__ inline float load_in(const void* p, size_t i, int bf) {
    return bf ? __bfloat162float(((const __hip_bfloat16*)p)[i])
              : ((const float*)p)[i];
}

// ---------------------------------------------------------------------------
// 0. dtype detection from mps bit patterns (bf16 ⇒ many nonzero low-halves)
// ---------------------------------------------------------------------------
__global__ void detect_dtype(const unsigned int* __restrict__ w, int nwords,
                             int* __restrict__ counter) {
    int stride = gridDim.x * blockDim.x;
    int c = 0;
    for (int i = blockIdx.x * blockDim.x + threadIdx.x; i < nwords; i += stride) {
        unsigned int x = w[i];
        if ((x & 0xFFFF0000u) == 0u && x != 0u) c++;
    }
    for (int s = 32; s > 0; s >>= 1) c += __shfl_down(c, s);
    if ((threadIdx.x & 63) == 0 && c > 0) atomicAdd(counter, c);
}

// ---------------------------------------------------------------------------
// 1. Convert all dense inputs to a contiguous bf16 staging area.
// ---------------------------------------------------------------------------
__global__ void convert_all(const void* h, const void* wg, const void* attw,
                            const void* w1, const void* w2, const void* bg,
                            const void* attb, const void* av, const void* pa,
                            const void* b1, const void* b2,
                            const int* __restrict__ counter,
                            __hip_bfloat16* __restrict__ dst) {
    int bf = get_bf(counter);
    const void* srcs[11] = {h, wg, attw, w1, w2, bg, attb, av, pa, b1, b2};
    const int offs[11] = {OFF_H, OFF_WG, OFF_ATTW, OFF_W1, OFF_W2, OFF_BG,
                          OFF_ATTB, OFF_AV, OFF_PA, OFF_B1, OFF_B2};
    const int lens[11] = {1048576, 196608, 65536, 65536, 65536, 768, 256, 256, 3, 256, 256};
    int stride = gridDim.x * blockDim.x;
    int t0 = blockIdx.x * blockDim.x + threadIdx.x;
    #pragma unroll
    for (int s = 0; s < 11; s++) {
        for (int i = t0; i < lens[s]; i += stride)
            dst[offs[s] + i] = __float2bfloat16(load_in(srcs[s], i, bf));
    }
}

// ---------------------------------------------------------------------------
// 2. Sparse extraction (per (p,n) row of mps), vectorized 16B loads.
// ---------------------------------------------------------------------------
__global__ void extract_sparse(const void* __restrict__ mps, const int* __restrict__ counter,
                               int* __restrict__ nbr_idx, float* __restrict__ nbr_val,
                               int* __restrict__ neg_idx, int* __restrict__ deg) {
    int bf = get_bf(counter);
    int row = blockIdx.x;              // 0 .. P*N-1
    int t = threadIdx.x;               // 256 threads, 16 elems each
    __shared__ int cnt;
    __shared__ int sidx[32];
    __shared__ float sval[32];
    if (t == 0) cnt = 0;
    __syncthreads();
    int e0 = t * 16;
    if (bf) {
        const uint4* base = (const uint4*)((const __hip_bfloat16*)mps + (size_t)row * N + e0);
        #pragma unroll
        for (int v = 0; v < 2; v++) {
            uint4 w = base[v];
            unsigned int ws[4] = {w.x, w.y, w.z, w.w};
            #pragma unroll
            for (int j = 0; j < 4; j++) {
                unsigned short lo = (unsigned short)(ws[j] & 0xFFFFu);
                unsigned short hi = (unsigned short)(ws[j] >> 16);
                if (lo) { int k = atomicAdd(&cnt, 1); if (k < 32) { sidx[k] = e0 + v * 8 + j * 2;     sval[k] = bfbits2f(lo); } }
                if (hi) { int k = atomicAdd(&cnt, 1); if (k < 32) { sidx[k] = e0 + v * 8 + j * 2 + 1; sval[k] = bfbits2f(hi); } }
            }
        }
    } else {
        const float4* base = (const float4*)((const float*)mps + (size_t)row * N + e0);
        #pragma unroll
        for (int v = 0; v < 4; v++) {
            float4 w = base[v];
            float ws[4] = {w.x, w.y, w.z, w.w};
            #pragma unroll
            for (int j = 0; j < 4; j++)
                if (ws[j] > 0.f) { int k = atomicAdd(&cnt, 1); if (k < 32) { sidx[k] = e0 + v * 4 + j; sval[k] = ws[j]; } }
        }
    }
    __syncthreads();
    if (t == 0) {
        int dg = cnt; if (dg > MAXDEG) dg = MAXDEG;
        for (int i = 1; i < dg; i++) {           // insertion sort by index
            int ki = sidx[i]; float kv = sval[i]; int j = i - 1;
            while (j >= 0 && sidx[j] > ki) { sidx[j+1] = sidx[j]; sval[j+1] = sval[j]; j--; }
            sidx[j+1] = ki; sval[j+1] = kv;
        }
        deg[row] = dg;
        int* oi = nbr_idx + (size_t)row * MAXDEG;
        float* ov = nbr_val + (size_t)row * MAXDEG;
        int* ng = neg_idx + (size_t)row * MAXDEG;
        for (int i = 0; i < MAXDEG; i++) { oi[i] = (i < dg) ? sidx[i] : 0; ov[i] = (i < dg) ? sval[i] : 0.f; }
        int c = 0, j = 0, found = 0;
        while (found < MAXDEG) {
            if (j < dg && sidx[j] == c) { j++; c++; continue; }
            ng[found++] = c++;
        }
    }
}

// ---------------------------------------------------------------------------
// 3. MFMA GEMM: C[z][r][c] = sum_k A[z][r][k]*B[z][c][k] (+bias)
//    64x64 tile, BK=32, 4 waves of 32x32. Used for X-stage and proj2.
// ---------------------------------------------------------------------------
template <int ACT>
__global__ void gemm_mfma(const __hip_bfloat16* __restrict__ Abase, size_t strideA,
                          const __hip_bfloat16* __restrict__ Bbase, size_t strideB,
                          const __hip_bfloat16* __restrict__ bias, size_t strideBias,
                          __hip_bfloat16* __restrict__ Cbase, size_t strideC) {
    int z = blockIdx.z;
    const __hip_bfloat16* A = Abase + (size_t)z * strideA;
    const __hip_bfloat16* B = Bbase + (size_t)z * strideB;
    __shared__ __align__(16) __hip_bfloat16 As[64 * LDP];
    __shared__ __align__(16) __hip_bfloat16 Bs[64 * LDP];
    int bm = blockIdx.x * 64, bn = blockIdx.y * 64;
    int tid = threadIdx.x, wave = tid >> 6, lane = tid & 63;
    int quad = lane >> 4, l15 = lane & 15;
    int wr = (wave & 1) * 32, wc = (wave >> 1) * 32;
    facc4 acc[2][2] = {};
    int sr = tid >> 2, kq = (tid & 3) * 8;
    for (int k0 = 0; k0 < D; k0 += 32) {
        *(bfrag8*)&As[sr * LDP + kq] = *(const bfrag8*)&A[(size_t)(bm + sr) * D + k0 + kq];
        *(bfrag8*)&Bs[sr * LDP + kq] = *(const bfrag8*)&B[(size_t)(bn + sr) * D + k0 + kq];
        __syncthreads();
        bfrag8 af[2], bfr[2];
        #pragma unroll
        for (int mi = 0; mi < 2; mi++)
            af[mi] = *(const bfrag8*)&As[(wr + mi * 16 + l15) * LDP + quad * 8];
        #pragma unroll
        for (int ni = 0; ni < 2; ni++)
            bfr[ni] = *(const bfrag8*)&Bs[(wc + ni * 16 + l15) * LDP + quad * 8];
        #pragma unroll
        for (int mi = 0; mi < 2; mi++)
            #pragma unroll
            for (int ni = 0; ni < 2; ni++)
                acc[mi][ni] = mfma16(af[mi], bfr[ni], acc[mi][ni]);
        __syncthreads();
    }
    #pragma unroll
    for (int mi = 0; mi < 2; mi++) {
        #pragma unroll
        for (int ni = 0; ni < 2; ni++) {
            int col = bn + wc + ni * 16 + l15;
            #pragma unroll
            for (int r = 0; r < 4; r++) {
                int row = bm + wr + mi * 16 + quad * 4 + r;
                float v = acc[mi][ni][r];
                if (bias) v += b2f(bias[col]);
                if (ACT == 1) v = v > 0.f ? v : expm1f(v);
                Cbase[(size_t)z * strideC + (size_t)row * D + col] = __float2bfloat16(v);
            }
        }
    }
}

// ---------------------------------------------------------------------------
// 3b. Fused dual-B GEMM over emb: shares A staging.
//     path 1: tanh(emb@attW^T + attb) → column-sum into spacc (no C write)
//     path 2: elu(emb@W1^T + b1) → xbuf
// ---------------------------------------------------------------------------
__global__ void gemm_dual(const __hip_bfloat16* __restrict__ embBase,
                          const __hip_bfloat16* __restrict__ conv,
                          __hip_bfloat16* __restrict__ xbuf,
                          float* __restrict__ spacc) {
    int z = blockIdx.z;
    const __hip_bfloat16* A = embBase + (size_t)z * N * D;
    const __hip_bfloat16* Ba = conv + OFF_ATTW;
    const __hip_bfloat16* Bw = conv + OFF_W1;
    __shared__ __align__(16) __hip_bfloat16 As[64 * LDP];
    __shared__ __align__(16) __hip_bfloat16 Bsa[64 * LDP];
    __shared__ __align__(16) __hip_bfloat16 Bsw[64 * LDP];
    int bm = blockIdx.x * 64, bn = blockIdx.y * 64;
    int tid = threadIdx.x, wave = tid >> 6, lane = tid & 63;
    int quad = lane >> 4, l15 = lane & 15;
    int wr = (wave & 1) * 32, wc = (wave >> 1) * 32;
    facc4 accA[2][2] = {};
    facc4 accW[2][2] = {};
    int sr = tid >> 2, kq = (tid & 3) * 8;
    for (int k0 = 0; k0 < D; k0 += 32) {
        *(bfrag8*)&As[sr * LDP + kq]  = *(const bfrag8*)&A[(size_t)(bm + sr) * D + k0 + kq];
        *(bfrag8*)&Bsa[sr * LDP + kq] = *(const bfrag8*)&Ba[(size_t)(bn + sr) * D + k0 + kq];
        *(bfrag8*)&Bsw[sr * LDP + kq] = *(const bfrag8*)&Bw[(size_t)(bn + sr) * D + k0 + kq];
        __syncthreads();
        bfrag8 af[2], ba[2], bw[2];
        #pragma unroll
        for (int mi = 0; mi < 2; mi++)
            af[mi] = *(const bfrag8*)&As[(wr + mi * 16 + l15) * LDP + quad * 8];
        #pragma unroll
        for (int ni = 0; ni < 2; ni++) {
            ba[ni] = *(const bfrag8*)&Bsa[(wc + ni * 16 + l15) * LDP + quad * 8];
            bw[ni] = *(const bfrag8*)&Bsw[(wc + ni * 16 + l15) * LDP + quad * 8];
        }
        #pragma unroll
        for (int mi = 0; mi < 2; mi++)
            #pragma unroll
            for (int ni = 0; ni < 2; ni++) {
                accA[mi][ni] = mfma16(af[mi], ba[ni], accA[mi][ni]);
                accW[mi][ni] = mfma16(af[mi], bw[ni], accW[mi][ni]);
            }
        __syncthreads();
    }
    float cs[2] = {0.f, 0.f};
    #pragma unroll
    for (int mi = 0; mi < 2; mi++) {
        #pragma unroll
        for (int ni = 0; ni < 2; ni++) {
            int col = bn + wc + ni * 16 + l15;
            float battb = b2f(conv[OFF_ATTB + col]);
            float bb1   = b2f(conv[OFF_B1 + col]);
            #pragma unroll
            for (int r = 0; r < 4; r++) {
                int row = bm + wr + mi * 16 + quad * 4 + r;
                cs[ni] += tanhf(accA[mi][ni][r] + battb);
                float v = accW[mi][ni][r] + bb1;
                v = v > 0.f ? v : expm1f(v);
                xbuf[(size_t)z * N * D + (size_t)row * D + col] = __float2bfloat16(v);
            }
        }
    }
    #pragma unroll
    for (int ni = 0; ni < 2; ni++) {
        float v = cs[ni];
        v += __shfl_xor(v, 16); v += __shfl_xor(v, 32);
        if (quad == 0) {
            int col = bn + wc + ni * 16 + l15;
            atomicAdd(&spacc[(size_t)z * D + col], v);
        }
    }
}

// ---------------------------------------------------------------------------
// 4. spmm + prelu: wave per node, ushort4 loads/stores.
// ---------------------------------------------------------------------------
__global__ void spmm_prelu(const __hip_bfloat16* __restrict__ Xbase,
                           const int* __restrict__ nbr_idx, const float* __restrict__ nbr_val,
                           const int* __restrict__ deg, const __hip_bfloat16* __restrict__ conv,
                           __hip_bfloat16* __restrict__ embBase) {
    int z = blockIdx.z;
    int wave = threadIdx.x >> 6, lane = threadIdx.x & 63;
    int n = blockIdx.x * 4 + wave;
    const __hip_bfloat16* X = Xbase + (size_t)z * N * D;
    const int* idx = nbr_idx + ((size_t)z * N + n) * MAXDEG;
    const float* val = nbr_val + ((size_t)z * N + n) * MAXDEG;
    int dg = deg[z * N + n];
    float acc[4] = {0.f, 0.f, 0.f, 0.f};
    for (int k = 0; k < dg; k++) {
        int j = idx[k];
        float vk = val[k];
        ushort4 x = *(const ushort4*)&X[(size_t)j * D + lane * 4];
        acc[0] += vk * bfbits2f(x.x); acc[1] += vk * bfbits2f(x.y);
        acc[2] += vk * bfbits2f(x.z); acc[3] += vk * bfbits2f(x.w);
    }
    ushort4 bb = *(const ushort4*)&conv[OFF_BG + z * D + lane * 4];
    float b[4] = {bfbits2f(bb.x), bfbits2f(bb.y), bfbits2f(bb.z), bfbits2f(bb.w)};
    float a = b2f(conv[OFF_PA + z]);
    ushort4 o;
    float v0 = acc[0] + b[0]; o.x = f2bfbits(v0 > 0.f ? v0 : a * v0);
    float v1 = acc[1] + b[1]; o.y = f2bfbits(v1 > 0.f ? v1 : a * v1);
    float v2 = acc[2] + b[2]; o.z = f2bfbits(v2 > 0.f ? v2 : a * v2);
    float v3 = acc[3] + b[3]; o.w = f2bfbits(v3 > 0.f ? v3 : a * v3);
    *(ushort4*)&embBase[(size_t)z * N * D + (size_t)n * D + lane * 4] = o;
}

// ---------------------------------------------------------------------------
// 5. Row-normalize bf16 in place: wave per row, shuffle reduce.
// ---------------------------------------------------------------------------
__global__ void rownorm(__hip_bfloat16* __restrict__ qbase) {
    int z = blockIdx.z;
    int wave = threadIdx.x >> 6, lane = threadIdx.x & 63;
    int n = blockIdx.x * 4 + wave;
    __hip_bfloat16* row = qbase + ((size_t)z * N + n) * D;
    ushort4 r = *(const ushort4*)&row[lane * 4];
    float v[4] = {bfbits2f(r.x), bfbits2f(r.y), bfbits2f(r.z), bfbits2f(r.w)};
    float ss = v[0] * v[0] + v[1] * v[1] + v[2] * v[2] + v[3] * v[3];
    #pragma unroll
    for (int s = 1; s <= 32; s <<= 1) ss += __shfl_xor(ss, s);
    float inv = rsqrtf(ss + 1e-30f);
    ushort4 o;
    o.x = f2bfbits(v[0] * inv); o.y = f2bfbits(v[1] * inv);
    o.z = f2bfbits(v[2] * inv); o.w = f2bfbits(v[3] * inv);
    *(ushort4*)&row[lane * 4] = o;
}

// ---------------------------------------------------------------------------
// 6. sim MFMA: per pair z, S = exp(Qz @ Q2^T / TAU) → rowsum/colsum atomics.
//    128x128 tile, 4 waves of 64x64 (16 accs), BK=64 (half the barriers).
// ---------------------------------------------------------------------------
__global__ void sim_mfma(const __hip_bfloat16* __restrict__ q,
                         float* __restrict__ rowsum, float* __restrict__ colsum) {
    int pair = blockIdx.z;
    const __hip_bfloat16* Qa = q + (size_t)pair * N * D;
    const __hip_bfloat16* Qb = q + (size_t)2 * N * D;
    __shared__ __align__(16) __hip_bfloat16 As[128 * LDK];
    __shared__ __align__(16) __hip_bfloat16 Bs[128 * LDK];
    int bm = blockIdx.x * 128, bn = blockIdx.y * 128;
    int tid = threadIdx.x, wave = tid >> 6, lane = tid & 63;
    int quad = lane >> 4, l15 = lane & 15;
    int wr = (wave & 1) * 64, wc = (wave >> 1) * 64;
    facc4 acc[4][4] = {};
    int sr0 = tid >> 3, kq = (tid & 7) * 8;      // 32 rows per chunk, 64 k-cols
    for (int k0 = 0; k0 < D; k0 += 64) {
        #pragma unroll
        for (int i = 0; i < 4; i++) {
            int r = sr0 + 32 * i;
            *(bfrag8*)&As[r * LDK + kq] = *(const bfrag8*)&Qa[(size_t)(bm + r) * D + k0 + kq];
            *(bfrag8*)&Bs[r * LDK + kq] = *(const bfrag8*)&Qb[(size_t)(bn + r) * D + k0 + kq];
        }
        __syncthreads();
        #pragma unroll
        for (int kk = 0; kk < 64; kk += 32) {
            bfrag8 af[4], bfr[4];
            #pragma unroll
            for (int mi = 0; mi < 4; mi++)
                af[mi] = *(const bfrag8*)&As[(wr + mi * 16 + l15) * LDK + kk + quad * 8];
            #pragma unroll
            for (int ni = 0; ni < 4; ni++)
                bfr[ni] = *(const bfrag8*)&Bs[(wc + ni * 16 + l15) * LDK + kk + quad * 8];
            #pragma unroll
            for (int mi = 0; mi < 4; mi++)
                #pragma unroll
                for (int ni = 0; ni < 4; ni++)
                    acc[mi][ni] = mfma16(af[mi], bfr[ni], acc[mi][ni]);
        }
        __syncthreads();
    }
    constexpr float invtau = 1.0f / TAU;
    float rs[4][4];   // [mi][r]
    float cs[4] = {0.f, 0.f, 0.f, 0.f};
    #pragma unroll
    for (int mi = 0; mi < 4; mi++)
        #pragma unroll
        for (int r = 0; r < 4; r++) rs[mi][r] = 0.f;
    #pragma unroll
    for (int mi = 0; mi < 4; mi++)
        #pragma unroll
        for (int ni = 0; ni < 4; ni++)
            #pragma unroll
            for (int r = 0; r < 4; r++) {
                float e = __expf(acc[mi][ni][r] * invtau);
                rs[mi][r] += e;
                cs[ni] += e;
            }
    #pragma unroll
    for (int mi = 0; mi < 4; mi++)
        #pragma unroll
        for (int r = 0; r < 4; r++) {
            float v = rs[mi][r];
            v += __shfl_xor(v, 1); v += __shfl_xor(v, 2);
            v += __shfl_xor(v, 4); v += __shfl_xor(v, 8);
            rs[mi][r] = v;
        }
    if (l15 == 0) {
        #pragma unroll
        for (int mi = 0; mi < 4; mi++)
            #pragma unroll
            for (int r = 0; r < 4; r++)
                atomicAdd(&rowsum[(size_t)pair * N + bm + wr + mi * 16 + quad * 4 + r], rs[mi][r]);
    }
    #pragma unroll
    for (int ni = 0; ni < 4; ni++) {
        float v = cs[ni];
        v += __shfl_xor(v, 16); v += __shfl_xor(v, 32);
        if (quad == 0)
            atomicAdd(&colsum[(size_t)pair * N + bn + wc + ni * 16 + l15], v);
    }
}

// ---------------------------------------------------------------------------
// 7. pos-weighted sums, one wave per node, vector loads.
// ---------------------------------------------------------------------------
__global__ void posdot(const __hip_bfloat16* __restrict__ q,
                       const int* __restrict__ nbr_idx, const float* __restrict__ nbr_val,
                       const int* __restrict__ deg,
                       float* __restrict__ pdrow, float* __restrict__ pdcol) {
    int pair = blockIdx.z;
    int wave = threadIdx.x >> 6, lane = threadIdx.x & 63;
    int n = blockIdx.x * 4 + wave;
    const __hip_bfloat16* Qa = q + (size_t)pair * N * D;
    const __hip_bfloat16* Qb = q + (size_t)2 * N * D;
    int dg = deg[pair * N + n];
    const int* idx = nbr_idx + ((size_t)pair * N + n) * MAXDEG;
    const float* val = nbr_val + ((size_t)pair * N + n) * MAXDEG;
    const float invtau = 1.0f / TAU;
    ushort4 ar = *(const ushort4*)&Qa[(size_t)n * D + lane * 4];
    ushort4 br = *(const ushort4*)&Qb[(size_t)n * D + lane * 4];
    float a[4] = {bfbits2f(ar.x), bfbits2f(ar.y), bfbits2f(ar.z), bfbits2f(ar.w)};
    float b[4] = {bfbits2f(br.x), bfbits2f(br.y), bfbits2f(br.z), bfbits2f(br.w)};
    float sr = 0.f, sc = 0.f;
    for (int k = 0; k < dg; k++) {
        int j = idx[k];
        ushort4 pj = *(const ushort4*)&Qb[(size_t)j * D + lane * 4];
        ushort4 aj = *(const ushort4*)&Qa[(size_t)j * D + lane * 4];
        float dr = a[0] * bfbits2f(pj.x) + a[1] * bfbits2f(pj.y) +
                   a[2] * bfbits2f(pj.z) + a[3] * bfbits2f(pj.w);
        float dc = b[0] * bfbits2f(aj.x) + b[1] * bfbits2f(aj.y) +
                   b[2] * bfbits2f(aj.z) + b[3] * bfbits2f(aj.w);
        #pragma unroll
        for (int s = 1; s <= 32; s <<= 1) { dr += __shfl_xor(dr, s); dc += __shfl_xor(dc, s); }
        sr += __expf(dr * invtau) * val[k];
        sc += __expf(dc * invtau) * val[k];
    }
    if (lane == 0) { pdrow[pair * N + n] = sr; pdcol[pair * N + n] = sc; }
}

// ---------------------------------------------------------------------------
// 8. node loss: one wave per node, partials to buffer (no atomics).
// ---------------------------------------------------------------------------
__global__ void node_loss_k(const __hip_bfloat16* __restrict__ embBase,
                            const int* __restrict__ nbr_idx, const int* __restrict__ neg_idx,
                            const int* __restrict__ deg, float* __restrict__ nlpart) {
    int z = blockIdx.z;
    int wave = threadIdx.x >> 6, lane = threadIdx.x & 63;
    int n = blockIdx.x * 4 + wave;
    const __hip_bfloat16* emb = embBase + (size_t)z * N * D;
    int dg = deg[z * N + n];
    const int* ip = nbr_idx + ((size_t)z * N + n) * MAXDEG;
    const int* ig = neg_idx + ((size_t)z * N + n) * MAXDEG;
    ushort4 ar = *(const ushort4*)&emb[(size_t)n * D + lane * 4];
    float a[4] = {bfbits2f(ar.x), bfbits2f(ar.y), bfbits2f(ar.z), bfbits2f(ar.w)};
    float s = 0.f;
    for (int k = 0; k < dg; k++) {
        int jp = ip[k], jn = ig[k];
        ushort4 pr = *(const ushort4*)&emb[(size_t)jp * D + lane * 4];
        ushort4 nr = *(const ushort4*)&emb[(size_t)jn * D + lane * 4];
        float pv[4] = {bfbits2f(pr.x), bfbits2f(pr.y), bfbits2f(pr.z), bfbits2f(pr.w)};
        float nv[4] = {bfbits2f(nr.x), bfbits2f(nr.y), bfbits2f(nr.z), bfbits2f(nr.w)};
        float dp = 0.f, dn = 0.f;
        #pragma unroll
        for (int i = 0; i < 4; i++) {
            float x = a[i] - pv[i] + EPS_PD; dp += x * x;
            float y = a[i] - nv[i] + EPS_PD; dn += y * y;
        }
        #pragma unroll
        for (int st = 1; st <= 32; st <<= 1) { dp += __shfl_xor(dp, st); dn += __shfl_xor(dn, st); }
        float v = dp - dn + MARGIN;
        s += v > 0.f ? v : 0.f;
    }
    if (lane == 0) nlpart[z * N + n] = s / (float)dg;
}

// ---------------------------------------------------------------------------
// 9. final loss + beta: single block, no atomics.
// ---------------------------------------------------------------------------
__global__ void reduce_loss_beta(const float* __restrict__ nlpart,
                                 const float* __restrict__ rowsum, const float* __restrict__ colsum,
                                 const float* __restrict__ pdrow, const float* __restrict__ pdcol,
                                 const float* __restrict__ spacc,
                                 const __hip_bfloat16* __restrict__ conv,
                                 float* __restrict__ beta, float* __restrict__ loss) {
    int t = threadIdx.x;
    __shared__ float red[256];
    __shared__ float w[P];
    for (int p = 0; p < P; p++) {
        float v = (spacc[p * D + t] / (float)N) * b2f(conv[OFF_AV + t]);
        red[t] = v;
        __syncthreads();
        for (int s = 128; s > 0; s >>= 1) { if (t < s) red[t] += red[t + s]; __syncthreads(); }
        if (t == 0) w[p] = red[0];
        __syncthreads();
    }
    float s = 0.f;
    for (int i = t; i < P * N; i += 256) s += nlpart[i];
    for (int i = t; i < 2 * N; i += 256) {
        float l12 = -logf(pdrow[i] / (rowsum[i] + 1e-8f));
        float l21 = -logf(pdcol[i] / (colsum[i] + 1e-8f));
        s += (0.5f * l12 + 0.5f * l21) / (float)N;
    }
    red[t] = s;
    __syncthreads();
    for (int st = 128; st > 0; st >>= 1) { if (t < st) red[t] += red[t + st]; __syncthreads(); }
    if (t == 0) {
        loss[0] = red[0];
        float m = fmaxf(w[0], fmaxf(w[1], w[2]));
        float e0 = __expf(w[0] - m), e1 = __expf(w[1] - m), e2 = __expf(w[2] - m);
        float ssum = e0 + e1 + e2;
        beta[0] = e0 / ssum; beta[1] = e1 / ssum; beta[2] = e2 / ssum;
    }
}

// ---------------------------------------------------------------------------
// 10. z_mp output + loss scalar (output dtype follows detected input dtype)
// ---------------------------------------------------------------------------
__global__ void zmp_out(const __hip_bfloat16* __restrict__ embBase, const float* __restrict__ beta,
                        const float* __restrict__ loss, const int* __restrict__ counter,
                        void* __restrict__ out) {
    int bf = get_bf(counter);
    int i = blockIdx.x * 256 + threadIdx.x;
    float v = beta[0] * b2f(embBase[i]) + beta[1] * b2f(embBase[(size_t)N * D + i]) +
              beta[2] * b2f(embBase[(size_t)2 * N * D + i]);
    if (bf) {
        __hip_bfloat16* o = (__hip_bfloat16*)out;
        o[i] = __float2bfloat16(v);
        if (i == 0) o[(size_t)N * D] = __float2bfloat16(*loss);
    } else {
        float* o = (float*)out;
        o[i] = v;
        if (i == 0) o[(size_t)N * D] = *loss;
    }
}

extern "C" void kernel_launch(void* const* d_in, const int* in_sizes, int n_in,
                              void* d_out, int out_size, void* d_ws, size_t ws_size,
                              hipStream_t stream) {
    const void* h        = d_in[0];
    const void* mps      = d_in[1];
    const void* W_gcn    = d_in[2];
    const void* b_gcn    = d_in[3];
    const void* prelu_a  = d_in[4];
    const void* att_fc_W = d_in[5];
    const void* att_fc_b = d_in[6];
    const void* att_vec  = d_in[7];
    const void* proj_W1  = d_in[8];
    const void* proj_b1  = d_in[9];
    const void* proj_W2  = d_in[10];
    const void* proj_b2  = d_in[11];

    char* ws = (char*)d_ws;
    size_t off = 0;
    auto alloc = [&](size_t bytes) -> char* {
        char* p = ws + off;
        off = (off + bytes + 255) & ~(size_t)255;
        return p;
    };
    __hip_bfloat16* conv = (__hip_bfloat16*)alloc((size_t)CONV_TOTAL * 2);
    __hip_bfloat16* xbuf = (__hip_bfloat16*)alloc((size_t)P * N * D * 2);
    __hip_bfloat16* emb  = (__hip_bfloat16*)alloc((size_t)P * N * D * 2);
    __hip_bfloat16* q    = (__hip_bfloat16*)alloc((size_t)P * N * D * 2);
    int*   nbr_idx = (int*)alloc((size_t)P * N * MAXDEG * 4);
    float* nbr_val = (float*)alloc((size_t)P * N * MAXDEG * 4);
    int*   neg_idx = (int*)alloc((size_t)P * N * MAXDEG * 4);
    int*   deg     = (int*)alloc((size_t)P * N * 4);
    float* nlpart  = (float*)alloc((size_t)P * N * 4);
    float* pdrow   = (float*)alloc((size_t)2 * N * 4);
    float* pdcol   = (float*)alloc((size_t)2 * N * 4);
    char* zero_begin = ws + off;
    float* rowsum = (float*)alloc((size_t)2 * N * 4);
    float* colsum = (float*)alloc((size_t)2 * N * 4);
    float* spacc  = (float*)alloc((size_t)P * D * 4);
    float* beta   = (float*)alloc(16);
    float* loss   = (float*)alloc(16);
    int*   counter = (int*)alloc(16);
    size_t zero_bytes = (size_t)((ws + off) - zero_begin);
    hipMemsetAsync(zero_begin, 0, zero_bytes, stream);

    // 0. dtype detection
    detect_dtype<<<1024, 256, 0, stream>>>((const unsigned int*)mps, 2 * 1024 * 1024, counter);

    // 1. convert dense inputs to bf16 staging
    convert_all<<<512, 256, 0, stream>>>(h, W_gcn, att_fc_W, proj_W1, proj_W2, b_gcn,
                                         att_fc_b, att_vec, prelu_a, proj_b1, proj_b2,
                                         counter, conv);

    // 2. sparse extraction
    extract_sparse<<<P * N, 256, 0, stream>>>(mps, counter, nbr_idx, nbr_val, neg_idx, deg);

    dim3 ggrid(N / 64, D / 64, P);
    size_t nd = (size_t)N * D;
    // 3. GCN: X[z] = h @ Wg[z]^T
    gemm_mfma<0><<<ggrid, 256, 0, stream>>>(
        conv + OFF_H, 0, conv + OFF_WG, (size_t)D * D, nullptr, 0, xbuf, nd);
    // 4. emb[z] = prelu(spmm + bias)
    spmm_prelu<<<dim3(N / 4, 1, P), 256, 0, stream>>>(xbuf, nbr_idx, nbr_val, deg, conv, emb);
    // 5+6a. fused: spacc = colsum(tanh(emb@attW^T+attb)); xbuf = elu(emb@W1^T+b1)
    gemm_dual<<<ggrid, 256, 0, stream>>>(emb, conv, xbuf, spacc);
    // 6b. q[z] = xbuf[z] @ W2^T + b2
    gemm_mfma<0><<<ggrid, 256, 0, stream>>>(
        xbuf, nd, conv + OFF_W2, 0, conv + OFF_B2, 0, q, nd);
    // 7. row-normalize q in place
    rownorm<<<dim3(N / 4, 1, P), 256, 0, stream>>>(q);
    // 8. sim (both pairs batched): rowsum/colsum
    sim_mfma<<<dim3(N / 128, N / 128, 2), 256, 0, stream>>>(q, rowsum, colsum);
    // 9. pos-weighted sums (wave per node)
    posdot<<<dim3(N / 4, 1, 2), 256, 0, stream>>>(q, nbr_idx, nbr_val, deg, pdrow, pdcol);
    // 10. node losses (wave per node, partials)
    node_loss_k<<<dim3(N / 4, 1, P), 256, 0, stream>>>(emb, nbr_idx, neg_idx, deg, nlpart);
    // 11. final loss + beta (no atomics)
    reduce_loss_beta<<<1, 256, 0, stream>>>(nlpart, rowsum, colsum, pdrow, pdcol,
                                            spacc, conv, beta, loss);
    // 12. output
    zmp_out<<<(N * D) / 256, 256, 0, stream>>>(emb, beta, loss, counter, d_out);
}